// Round 4
// baseline (873.216 us; speedup 1.0000x reference)
//
#include <hip/hip_runtime.h>
#include <hip/hip_bf16.h>
#include <math.h>

#define CS  1024
#define CB  2
#define CD  1024
#define CN  16
#define CDH 64
#define CDI 4096
#define CR  2048
#define CL  2

typedef __bf16 bf16x8 __attribute__((ext_vector_type(8)));
typedef float  f32x4  __attribute__((ext_vector_type(4)));

__device__ __forceinline__ unsigned short f2b(float f) {
    unsigned int u = __float_as_uint(f);
    u += 0x7FFF + ((u >> 16) & 1);          // RNE
    return (unsigned short)(u >> 16);
}

// async global->LDS 16B per lane: lane i lands at ldsbase + i*16 (wave-uniform base)
__device__ __forceinline__ void gl_lds16(const void* g, void* l) {
    __builtin_amdgcn_global_load_lds(
        (const __attribute__((address_space(1))) unsigned int*)g,
        (__attribute__((address_space(3))) unsigned int*)l, 16, 0, 0);
}

// ---------------------------------------------------------------------------
// flat fp32 -> bf16 convert (x4)
// ---------------------------------------------------------------------------
__global__ __launch_bounds__(256) void convert_f2b_kernel(
    const float* __restrict__ in, unsigned short* __restrict__ out, int n4)
{
    const int i = blockIdx.x * 256 + threadIdx.x;
    if (i >= n4) return;
    const float4 v = ((const float4*)in)[i];
    ushort4 o;
    o.x = f2b(v.x); o.y = f2b(v.y); o.z = f2b(v.z); o.w = f2b(v.w);
    ((ushort4*)out)[i] = o;
}

// ---------------------------------------------------------------------------
// fp32 [K,N] -> bf16 [N,K] transpose-convert
// ---------------------------------------------------------------------------
__global__ __launch_bounds__(256) void transpose_f2b_kernel(
    const float* __restrict__ in, unsigned short* __restrict__ out, int K, int N)
{
    __shared__ unsigned short t[32][33];
    const int k0 = blockIdx.y * 32, n0 = blockIdx.x * 32;
    const int c = threadIdx.x & 31, r0 = threadIdx.x >> 5;
    for (int r = r0; r < 32; r += 8)
        t[r][c] = f2b(in[(size_t)(k0 + r) * N + n0 + c]);
    __syncthreads();
    for (int r = r0; r < 32; r += 8)
        out[(size_t)(n0 + r) * K + k0 + c] = t[c][r];
}

// ---------------------------------------------------------------------------
// m97-style bf16 MFMA GEMM: C = A[M,K] @ Bt[N,K]^T, global_load_lds staging.
// LDS tiles unpadded [rows][32] bf16. 4 waves 2x2.
// EPI bits: 1=bias 2=gelu 4=res 8=bf16 out(D1) 16=split3 (C0 fp32|D1|D2 bf16)
// ---------------------------------------------------------------------------
template<int FM, int FN, int EPI>
__global__ __launch_bounds__(256) void mgemm(
    const __bf16* __restrict__ A, const __bf16* __restrict__ Bt,
    float* __restrict__ C0, __bf16* __restrict__ D1, __bf16* __restrict__ D2,
    int M, int N, int K,
    const float* __restrict__ bias, const float* __restrict__ res)
{
    constexpr int TM = 32 * FM, TN = 32 * FN;
    __shared__ __align__(16) __bf16 As[TM * 32];
    __shared__ __align__(16) __bf16 Bs[TN * 32];
    const int tid  = threadIdx.x;
    const int wave = tid >> 6, lane = tid & 63;
    const int q = lane >> 4, p = lane & 15;
    const int m0 = blockIdx.y * TM, n0 = blockIdx.x * TN;
    const int wm = (wave & 1) * (16 * FM);
    const int wn = (wave >> 1) * (16 * FN);
    const int lrow = lane >> 2;          // 0..15
    const int lcol = (lane & 3) * 8;     // 0,8,16,24

    f32x4 acc[FM][FN];
#pragma unroll
    for (int i = 0; i < FM; ++i)
#pragma unroll
        for (int j = 0; j < FN; ++j) {
            acc[i][j][0] = 0.f; acc[i][j][1] = 0.f;
            acc[i][j][2] = 0.f; acc[i][j][3] = 0.f;
        }

    for (int k0 = 0; k0 < K; k0 += 32) {
#pragma unroll
        for (int c = wave; c < TM / 16; c += 4)
            gl_lds16(A + (size_t)(m0 + c * 16 + lrow) * K + k0 + lcol,
                     As + c * 16 * 32);
#pragma unroll
        for (int c = wave; c < TN / 16; c += 4)
            gl_lds16(Bt + (size_t)(n0 + c * 16 + lrow) * K + k0 + lcol,
                     Bs + c * 16 * 32);
        __syncthreads();
        bf16x8 af[FM], bfr[FN];
#pragma unroll
        for (int i = 0; i < FM; ++i)
            af[i] = *(const bf16x8*)(As + (wm + i * 16 + p) * 32 + q * 8);
#pragma unroll
        for (int j = 0; j < FN; ++j)
            bfr[j] = *(const bf16x8*)(Bs + (wn + j * 16 + p) * 32 + q * 8);
#pragma unroll
        for (int i = 0; i < FM; ++i)
#pragma unroll
            for (int j = 0; j < FN; ++j)
                acc[i][j] = __builtin_amdgcn_mfma_f32_16x16x32_bf16(
                    af[i], bfr[j], acc[i][j], 0, 0, 0);
        __syncthreads();
    }

    // C/D layout: col = lane&15, row = (lane>>4)*4 + reg
#pragma unroll
    for (int i = 0; i < FM; ++i) {
#pragma unroll
        for (int j = 0; j < FN; ++j) {
            const int col = n0 + wn + j * 16 + p;
            const float bv = (EPI & 1) ? bias[col] : 0.0f;
#pragma unroll
            for (int r = 0; r < 4; ++r) {
                const int row = m0 + wm + i * 16 + q * 4 + r;
                float v = acc[i][j][r] + bv;
                if (EPI & 2) v = 0.5f * v * (1.0f + erff(v * 0.70710678118654752f));
                if (EPI & 4) v += res[(size_t)row * N + col];
                if (EPI & 16) {
                    if (col < 1024)       C0[(size_t)row * 1024 + col] = v;
                    else if (col < 2048)  D1[(size_t)row * 1024 + col - 1024] = (__bf16)v;
                    else                  D2[(size_t)row * 1024 + col - 2048] = (__bf16)v;
                } else if (EPI & 8) {
                    D1[(size_t)row * N + col] = (__bf16)v;
                } else {
                    C0[(size_t)row * N + col] = v;
                }
            }
        }
    }
}

// ---------------------------------------------------------------------------
// seg_mat[S,S,B,2] -> byte segb[b][i][j]
// ---------------------------------------------------------------------------
__global__ __launch_bounds__(256) void segpack_kernel(
    const float* __restrict__ seg_mat, unsigned char* __restrict__ segb)
{
    const int idx = blockIdx.x * 256 + threadIdx.x;
    const int b   = idx / (CS * CS);
    const int rem = idx - b * (CS * CS);
    const int i   = rem >> 10;
    const int j   = rem & (CS - 1);
    segb[idx] = seg_mat[(((size_t)i * CS + j) * CB + b) * 2 + 1] > 0.5f ? 1 : 0;
}

// ---------------------------------------------------------------------------
// ef[s][i,b,n] = sum_d (qh + r_s_bias) * seg_embed[s]
// ---------------------------------------------------------------------------
__global__ __launch_bounds__(256) void ef_kernel(
    const float* __restrict__ qh, const float* __restrict__ rsb,
    const float* __restrict__ sege, float* __restrict__ ef)
{
    const int idx = blockIdx.x * 256 + threadIdx.x;
    const int n = idx & (CN - 1);
    const float* qp = qh + (size_t)idx * CDH;
    const float* sb = rsb + n * CDH;
    const float* s0 = sege + n * CDH;
    const float* s1 = sege + (CN + n) * CDH;
    float e0 = 0.f, e1 = 0.f;
#pragma unroll
    for (int d = 0; d < CDH; ++d) {
        const float qv = qp[d] + sb[d];
        e0 = fmaf(qv, s0[d], e0);
        e1 = fmaf(qv, s1[d], e1);
    }
    ef[idx] = e0;
    ef[CS * CB * CN + idx] = e1;
}

// ---------------------------------------------------------------------------
// MFMA flash attention, bf16 K/V/Kr inputs, shuffle-based rel-shift.
// Block = (b,n, 64 q-rows). LDS 52224 B -> 3 blocks/CU.
// ---------------------------------------------------------------------------
#define KSTR 40
#define VSTR 48
#define PSTR 72

__global__ __launch_bounds__(256, 3) void attn_mfma_kernel(
    const float* __restrict__ qh, const __bf16* __restrict__ khb,
    const __bf16* __restrict__ vhb, const __bf16* __restrict__ krb,
    const float* __restrict__ efb, const unsigned char* __restrict__ segb,
    const float* __restrict__ rwb, const float* __restrict__ rrb,
    __bf16* __restrict__ vecb)
{
    __shared__ __align__(16) char smem[52224];
    __bf16* Pl  = (__bf16*)(smem);             // [4][16][PSTR]  9216 B
    __bf16* Ks  = (__bf16*)(smem + 9216);      // [2][64][KSTR] 10240 B
    __bf16* Vt  = (__bf16*)(smem + 19456);     // [2][64][VSTR] 12288 B
    __bf16* Krs = (__bf16*)(smem + 31744);     // [2][128][KSTR] 20480 B

    const int bn = blockIdx.x;
    const int b = bn >> 4, n = bn & 15;
    const int itile = (int)gridDim.y - 1 - (int)blockIdx.y;  // heavy first
    const int i0 = itile * 64;
    const int tid = threadIdx.x;
    const int w = tid >> 6;
    const int lane = tid & 63;
    const int p = lane & 15, q = lane >> 4;

    // persistent Q fragments (A-layout)
    bf16x8 qwF[2], qrF[2];
    {
        const float* qrow = qh + (((size_t)(i0 + 16 * w + p) * CB + b) * CN + n) * CDH;
        const float* rw = rwb + n * CDH;
        const float* rr = rrb + n * CDH;
#pragma unroll
        for (int ks = 0; ks < 2; ++ks)
#pragma unroll
            for (int t = 0; t < 8; ++t) {
                const int d = ks * 32 + q * 8 + t;
                const float v = qrow[d];
                qwF[ks][t] = (__bf16)(v + rw[d]);
                qrF[ks][t] = (__bf16)(v + rr[d]);
            }
    }
    float ef0r[4], ef1r[4];
#pragma unroll
    for (int r = 0; r < 4; ++r) {
        const size_t e = ((size_t)(i0 + 16 * w + 4 * q + r) * CB + b) * CN + n;
        ef0r[r] = efb[e];
        ef1r[r] = efb[(size_t)CS * CB * CN + e];
    }

    f32x4 opv[4];
    float mrow[4], lrow[4];
#pragma unroll
    for (int nf = 0; nf < 4; ++nf) { opv[nf][0]=0.f; opv[nf][1]=0.f; opv[nf][2]=0.f; opv[nf][3]=0.f; }
#pragma unroll
    for (int r = 0; r < 4; ++r) { mrow[r] = -3.0e38f; lrow[r] = 0.f; }

    const int ntile = itile + 1;
    const unsigned char* sb = segb + (size_t)b * CS * CS;
    const int wbase = 48 - 16 * w;

    for (int jt = 0; jt < ntile; ++jt) {
        const int j0 = jt * 64;
        const int gs = j0 + CS - i0 - 63;      // in [1, 961]

        // ---- stage K (bf16), Kr band, V^T ----
        {
            const __bf16* kbase = khb + ((size_t)j0 * CB + b) * CN * CDH + n * CDH;
#pragma unroll
            for (int it = 0; it < 2; ++it) {
                const int idx = it * 256 + tid;
                const int row = idx >> 3, o = idx & 7;
                const uint4 v = *(const uint4*)(kbase + (size_t)row * (CB*CN*CDH) + o * 8);
                *(uint4*)(Ks + (o >> 2) * (64 * KSTR) + row * KSTR + (o & 3) * 8) = v;
            }
            const __bf16* krbase = krb + ((size_t)gs * CB + b) * CN * CDH + n * CDH;
#pragma unroll
            for (int it = 0; it < 4; ++it) {
                const int idx = it * 256 + tid;
                const int row = idx >> 3, o = idx & 7;
                const uint4 v = *(const uint4*)(krbase + (size_t)row * (CB*CN*CDH) + o * 8);
                *(uint4*)(Krs + (o >> 2) * (128 * KSTR) + row * KSTR + (o & 3) * 8) = v;
            }
            const int jp = tid >> 3, o = tid & 7;
            const int j = jp * 2;
            const __bf16* vbase = vhb + ((size_t)(j0 + j) * CB + b) * CN * CDH + n * CDH + o * 8;
            union { uint4 u; unsigned short s[8]; } a0, a1;
            a0.u = *(const uint4*)vbase;
            a1.u = *(const uint4*)(vbase + CB*CN*CDH);
            const int jh = j >> 5, jc = j & 31;
#pragma unroll
            for (int tt = 0; tt < 8; ++tt) {
                const int t = (tt + o) & 7;
                const unsigned int dw = (unsigned int)a0.s[t] | ((unsigned int)a1.s[t] << 16);
                *(unsigned int*)(Vt + jh * (64 * VSTR) + (o * 8 + t) * VSTR + jc) = dw;
            }
        }
        __syncthreads();

        // ---- ac (8 MFMA) + bd raw band (10 MFMA) ----
        f32x4 ac[4], rawacc[5];
#pragma unroll
        for (int nf = 0; nf < 4; ++nf) { ac[nf][0]=0.f; ac[nf][1]=0.f; ac[nf][2]=0.f; ac[nf][3]=0.f; }
#pragma unroll
        for (int t = 0; t < 5; ++t) { rawacc[t][0]=0.f; rawacc[t][1]=0.f; rawacc[t][2]=0.f; rawacc[t][3]=0.f; }
#pragma unroll
        for (int ks = 0; ks < 2; ++ks) {
#pragma unroll
            for (int nf = 0; nf < 4; ++nf) {
                const bf16x8 bf = *(const bf16x8*)(Ks + ks * (64 * KSTR) + (nf * 16 + p) * KSTR + q * 8);
                ac[nf] = __builtin_amdgcn_mfma_f32_16x16x32_bf16(qwF[ks], bf, ac[nf], 0, 0, 0);
            }
#pragma unroll
            for (int t = 0; t < 5; ++t) {
                const bf16x8 bf = *(const bf16x8*)(Krs + ks * (128 * KSTR) + (wbase + t * 16 + p) * KSTR + q * 8);
                rawacc[t] = __builtin_amdgcn_mfma_f32_16x16x32_bf16(qrF[ks], bf, rawacc[t], 0, 0, 0);
            }
        }

        // ---- rel-shift extraction via shuffles ----
        // bd(rl=4q+r, jj=nf*16+p) = band[rl][nf*16 + p + 15 - rl]
        float bd[4][4];
#pragma unroll
        for (int r = 0; r < 4; ++r) {
            const int rl = 4 * q + r;
            const int delta = p + 15 - rl;             // 0..30
            const int srcl = (q << 4) | (delta & 15);
            float sh[5];
#pragma unroll
            for (int t = 0; t < 5; ++t) sh[t] = __shfl(rawacc[t][r], srcl);
            const int hi = delta >> 4;
#pragma unroll
            for (int nf = 0; nf < 4; ++nf)
                bd[nf][r] = hi ? sh[nf + 1] : sh[nf];
        }

        // ---- scores + online softmax ----
        const bool diag = (jt == ntile - 1);
        float sc[4][4];
#pragma unroll
        for (int nf = 0; nf < 4; ++nf) {
            const int jj = nf * 16 + p;
#pragma unroll
            for (int r = 0; r < 4; ++r) {
                const int rl = 4 * q + r;
                const int ii = i0 + 16 * w + rl;
                const float e = sb[(size_t)ii * CS + (j0 + jj)] ? ef1r[r] : ef0r[r];
                float s = (ac[nf][r] + bd[nf][r] + e) * 0.125f;
                if (diag && jj > 16 * w + rl) s = -3.0e38f;
                sc[nf][r] = s;
            }
        }
        float al[4], ls[4];
#pragma unroll
        for (int r = 0; r < 4; ++r) {
            float m = fmaxf(fmaxf(sc[0][r], sc[1][r]), fmaxf(sc[2][r], sc[3][r]));
#pragma unroll
            for (int off = 1; off < 16; off <<= 1) m = fmaxf(m, __shfl_xor(m, off));
            const float mn = fmaxf(mrow[r], m);
            al[r] = __expf(mrow[r] - mn);
            mrow[r] = mn;
            ls[r] = 0.f;
        }
#pragma unroll
        for (int nf = 0; nf < 4; ++nf)
#pragma unroll
            for (int r = 0; r < 4; ++r) {
                const float pv = __expf(sc[nf][r] - mrow[r]);
                sc[nf][r] = pv;
                ls[r] += pv;
            }
#pragma unroll
        for (int r = 0; r < 4; ++r) {
            float s = ls[r];
#pragma unroll
            for (int off = 1; off < 16; off <<= 1) s += __shfl_xor(s, off);
            lrow[r] = lrow[r] * al[r] + s;
#pragma unroll
            for (int nf = 0; nf < 4; ++nf) opv[nf][r] *= al[r];
        }

        // ---- P C-layout -> LDS -> A-layout, then PV ----
        __bf16* pw = Pl + w * (16 * PSTR);
#pragma unroll
        for (int nf = 0; nf < 4; ++nf)
#pragma unroll
            for (int r = 0; r < 4; ++r)
                pw[(4 * q + r) * PSTR + nf * 16 + p] = (__bf16)sc[nf][r];

#pragma unroll
        for (int ks = 0; ks < 2; ++ks) {
            const bf16x8 pf = *(const bf16x8*)(pw + p * PSTR + ks * 32 + q * 8);
#pragma unroll
            for (int nf = 0; nf < 4; ++nf) {
                const bf16x8 vf = *(const bf16x8*)(Vt + ks * (64 * VSTR) + (nf * 16 + p) * VSTR + q * 8);
                opv[nf] = __builtin_amdgcn_mfma_f32_16x16x32_bf16(pf, vf, opv[nf], 0, 0, 0);
            }
        }
        __syncthreads();
    }

    // ---- epilogue: normalize, write vec bf16 ----
#pragma unroll
    for (int r = 0; r < 4; ++r) {
        const float ri = 1.0f / lrow[r];
        const int i = i0 + 16 * w + 4 * q + r;
        __bf16* op = vecb + (((size_t)i * CB + b) * CN + n) * CDH;
#pragma unroll
        for (int nf = 0; nf < 4; ++nf)
            op[nf * 16 + p] = (__bf16)(opv[nf][r] * ri);
    }
}

// ---------------------------------------------------------------------------
// LayerNorm over D=1024, optional bf16 shadow output
// ---------------------------------------------------------------------------
__global__ __launch_bounds__(256) void ln_kernel(
    const float* __restrict__ x, float* __restrict__ y,
    unsigned short* __restrict__ yb,
    const float* __restrict__ g, const float* __restrict__ bb)
{
    __shared__ float red[8];
    const int row = blockIdx.x;
    const int tid = threadIdx.x;
    const float4 v = ((const float4*)(x + (size_t)row * CD))[tid];
    float s = v.x + v.y + v.z + v.w;
#pragma unroll
    for (int off = 32; off; off >>= 1) s += __shfl_xor(s, off, 64);
    if ((tid & 63) == 0) red[tid >> 6] = s;
    __syncthreads();
    const float mean = (red[0] + red[1] + red[2] + red[3]) * (1.f / CD);
    const float d0 = v.x - mean, d1 = v.y - mean, d2 = v.z - mean, d3 = v.w - mean;
    float ss = d0 * d0 + d1 * d1 + d2 * d2 + d3 * d3;
#pragma unroll
    for (int off = 32; off; off >>= 1) ss += __shfl_xor(ss, off, 64);
    if ((tid & 63) == 0) red[4 + (tid >> 6)] = ss;
    __syncthreads();
    const float var  = (red[4] + red[5] + red[6] + red[7]) * (1.f / CD);
    const float rstd = rsqrtf(var + 1e-12f);
    const float4 gv = ((const float4*)g)[tid];
    const float4 bv = ((const float4*)bb)[tid];
    float4 o;
    o.x = d0 * rstd * gv.x + bv.x;
    o.y = d1 * rstd * gv.y + bv.y;
    o.z = d2 * rstd * gv.z + bv.z;
    o.w = d3 * rstd * gv.w + bv.w;
    ((float4*)(y + (size_t)row * CD))[tid] = o;
    if (yb) {
        ushort4 ob;
        ob.x = f2b(o.x); ob.y = f2b(o.y); ob.z = f2b(o.z); ob.w = f2b(o.w);
        ((ushort4*)(yb + (size_t)row * CD))[tid] = ob;
    }
}

// ---------------------------------------------------------------------------
// Workspace layout (MiB, total 74.25 proven):
//  [0,8) cur f32 | [8,16) qh f32 | [16,20) khb bf16 | [20,24) vhb bf16
//  [24,32) krb bf16 | [32,40) wbuf bf16 | [40,44) vec_b bf16 | [44,52) ax f32
//  [52,60) xb f32 | [60,64) cur_b/xb_b bf16 (time-shared) | [64,72) pos_b bf16
//  [72,72.25) efb | [72.25,74.25) segb
//  ffb bf16 [8,24) aliases qh/khb/vhb (dead at FFN time)
// ---------------------------------------------------------------------------
extern "C" void kernel_launch(void* const* d_in, const int* in_sizes, int n_in,
                              void* d_out, int out_size, void* d_ws, size_t ws_size,
                              hipStream_t stream)
{
    const float* h       = (const float*)d_in[0];
    const float* pos_emb = (const float*)d_in[1];
    const float* seg_mat = (const float*)d_in[3];
    const float* Wq  = (const float*)d_in[4];
    const float* Wk  = (const float*)d_in[5];
    const float* Wv  = (const float*)d_in[6];
    const float* Wo  = (const float*)d_in[7];
    const float* Wr  = (const float*)d_in[8];
    const float* rwb = (const float*)d_in[9];
    const float* rrb = (const float*)d_in[10];
    const float* rsb = (const float*)d_in[11];
    const float* sege = (const float*)d_in[12];
    const float* ln1g = (const float*)d_in[13];
    const float* ln1b = (const float*)d_in[14];
    const float* fw1  = (const float*)d_in[15];
    const float* fb1  = (const float*)d_in[16];
    const float* fw2  = (const float*)d_in[17];
    const float* fb2  = (const float*)d_in[18];
    const float* ln2g = (const float*)d_in[19];
    const float* ln2b = (const float*)d_in[20];
    float* out = (float*)d_out;

    char* base = (char*)d_ws;
    const size_t MB = 1u << 20;
    float* cur  = (float*)(base + 0 * MB);
    float* qh   = (float*)(base + 8 * MB);
    __bf16* khb = (__bf16*)(base + 16 * MB);
    __bf16* vhb = (__bf16*)(base + 20 * MB);
    __bf16* krb = (__bf16*)(base + 24 * MB);
    unsigned short* wbuf = (unsigned short*)(base + 32 * MB);
    __bf16* vec_b = (__bf16*)(base + 40 * MB);
    float* ax   = (float*)(base + 44 * MB);
    float* xb   = (float*)(base + 52 * MB);
    unsigned short* curxb_b = (unsigned short*)(base + 60 * MB);  // cur_b / xb_b
    unsigned short* pos_b = (unsigned short*)(base + 64 * MB);
    float* efb  = (float*)(base + 72 * MB);
    unsigned char* segb = (unsigned char*)(base + 72 * MB + (1u << 18));
    __bf16* ffb = (__bf16*)(base + 8 * MB);   // aliases qh/khb/vhb

    hipMemcpyAsync(cur, h, (size_t)CS * CB * CD * sizeof(float),
                   hipMemcpyDeviceToDevice, stream);
    convert_f2b_kernel<<<(CS * CB * CD / 4) / 256, 256, 0, stream>>>(
        h, curxb_b, CS * CB * CD / 4);
    convert_f2b_kernel<<<(CR * CB * CD / 4) / 256, 256, 0, stream>>>(
        pos_emb, pos_b, CR * CB * CD / 4);
    segpack_kernel<<<(CS * CS * CB) / 256, 256, 0, stream>>>(seg_mat, segb);

    const int MQ = CS * CB;   // 2048
    for (int l = 0; l < CL; ++l) {
        const size_t wOff = (size_t)l * CD * CN * CDH;
        // fused QKV: Bt = [WqT ; WkT ; WvT], outputs qh f32 + khb/vhb bf16
        transpose_f2b_kernel<<<dim3(32, 32), 256, 0, stream>>>(Wq + wOff, wbuf, CD, CD);
        transpose_f2b_kernel<<<dim3(32, 32), 256, 0, stream>>>(Wk + wOff, wbuf + 1024 * 1024, CD, CD);
        transpose_f2b_kernel<<<dim3(32, 32), 256, 0, stream>>>(Wv + wOff, wbuf + 2 * 1024 * 1024, CD, CD);
        mgemm<4, 4, 16><<<dim3(3072 / 128, MQ / 128), 256, 0, stream>>>(
            (const __bf16*)curxb_b, (const __bf16*)wbuf, qh, khb, vhb,
            MQ, 3072, CD, nullptr, nullptr);
        // R projection -> krb bf16
        transpose_f2b_kernel<<<dim3(32, 32), 256, 0, stream>>>(Wr + wOff, wbuf, CD, CD);
        mgemm<4, 4, 8><<<dim3(1024 / 128, (CR * CB) / 128), 256, 0, stream>>>(
            (const __bf16*)pos_b, (const __bf16*)wbuf, nullptr, krb, nullptr,
            CR * CB, CD, CD, nullptr, nullptr);
        ef_kernel<<<(CS * CB * CN) / 256, 256, 0, stream>>>(
            qh, rsb + (size_t)l * CN * CDH, sege + (size_t)l * 2 * CN * CDH, efb);
        attn_mfma_kernel<<<dim3(CB * CN, CS / 64), 256, 0, stream>>>(
            qh, khb, vhb, krb, efb, segb,
            rwb + (size_t)l * CN * CDH, rrb + (size_t)l * CN * CDH, vec_b);
        // Wo projection + residual (Wo already [h][n*d] = Bt layout)
        convert_f2b_kernel<<<(CD * CD / 4) / 256, 256, 0, stream>>>(Wo + wOff, wbuf, CD * CD / 4);
        mgemm<2, 4, 4><<<dim3(1024 / 128, MQ / 64), 256, 0, stream>>>(
            vec_b, (const __bf16*)wbuf, ax, nullptr, nullptr,
            MQ, CD, CD, nullptr, cur);
        ln_kernel<<<MQ, 256, 0, stream>>>(ax, xb, curxb_b, ln1g + l * CD, ln1b + l * CD);
        // FFN
        transpose_f2b_kernel<<<dim3(CDI / 32, CD / 32), 256, 0, stream>>>(
            fw1 + (size_t)l * CD * CDI, wbuf, CD, CDI);
        mgemm<4, 4, 1 | 2 | 8><<<dim3(CDI / 128, MQ / 128), 256, 0, stream>>>(
            (const __bf16*)curxb_b, (const __bf16*)wbuf, nullptr, ffb, nullptr,
            MQ, CDI, CD, fb1 + l * CDI, nullptr);
        transpose_f2b_kernel<<<dim3(CD / 32, CDI / 32), 256, 0, stream>>>(
            fw2 + (size_t)l * CDI * CD, wbuf, CDI, CD);
        mgemm<2, 4, 1 | 4><<<dim3(CD / 128, MQ / 64), 256, 0, stream>>>(
            ffb, (const __bf16*)wbuf, ax, nullptr, nullptr,
            MQ, CD, CDI, fb2 + l * CD, xb);
        if (l == CL - 1)
            ln_kernel<<<MQ, 256, 0, stream>>>(ax, out, nullptr, ln2g + l * CD, ln2b + l * CD);
        else
            ln_kernel<<<MQ, 256, 0, stream>>>(ax, cur, curxb_b, ln2g + l * CD, ln2b + l * CD);
    }
}

// Round 5
// 827.110 us; speedup vs baseline: 1.0557x; 1.0557x over previous
//
#include <hip/hip_runtime.h>
#include <hip/hip_bf16.h>
#include <math.h>

#define CS  1024
#define CB  2
#define CD  1024
#define CN  16
#define CDH 64
#define CDI 4096
#define CR  2048
#define CL  2

typedef __bf16 bf16x8 __attribute__((ext_vector_type(8)));
typedef float  f32x4  __attribute__((ext_vector_type(4)));

__device__ __forceinline__ unsigned short f2b(float f) {
    unsigned int u = __float_as_uint(f);
    u += 0x7FFF + ((u >> 16) & 1);          // RNE
    return (unsigned short)(u >> 16);
}

// async global->LDS 16B per lane: lane i lands at ldsbase + i*16 (wave-uniform base)
__device__ __forceinline__ void gl_lds16(const void* g, void* l) {
    __builtin_amdgcn_global_load_lds(
        (const __attribute__((address_space(1))) unsigned int*)g,
        (__attribute__((address_space(3))) unsigned int*)l, 16, 0, 0);
}

// ---------------------------------------------------------------------------
// flat fp32 -> bf16 convert (x4)
// ---------------------------------------------------------------------------
__global__ __launch_bounds__(256) void convert_f2b_kernel(
    const float* __restrict__ in, unsigned short* __restrict__ out, int n4)
{
    const int i = blockIdx.x * 256 + threadIdx.x;
    if (i >= n4) return;
    const float4 v = ((const float4*)in)[i];
    ushort4 o;
    o.x = f2b(v.x); o.y = f2b(v.y); o.z = f2b(v.z); o.w = f2b(v.w);
    ((ushort4*)out)[i] = o;
}

// ---------------------------------------------------------------------------
// fp32 [K,N] -> bf16 [N,K] transpose-convert
// ---------------------------------------------------------------------------
__global__ __launch_bounds__(256) void transpose_f2b_kernel(
    const float* __restrict__ in, unsigned short* __restrict__ out, int K, int N)
{
    __shared__ unsigned short t[32][33];
    const int k0 = blockIdx.y * 32, n0 = blockIdx.x * 32;
    const int c = threadIdx.x & 31, r0 = threadIdx.x >> 5;
    for (int r = r0; r < 32; r += 8)
        t[r][c] = f2b(in[(size_t)(k0 + r) * N + n0 + c]);
    __syncthreads();
    for (int r = r0; r < 32; r += 8)
        out[(size_t)(n0 + r) * K + k0 + c] = t[c][r];
}

// ---------------------------------------------------------------------------
// m97-style bf16 MFMA GEMM: C = A[M,K] @ Bt[N,K]^T, global_load_lds staging.
// LDS tiles unpadded [rows][32] bf16. 4 waves 2x2.
// EPI bits: 1=bias 2=gelu 4=res 8=bf16 out(D1) 16=split3 (C0 fp32|D1|D2 bf16)
// ---------------------------------------------------------------------------
template<int FM, int FN, int EPI>
__global__ __launch_bounds__(256) void mgemm(
    const __bf16* __restrict__ A, const __bf16* __restrict__ Bt,
    float* __restrict__ C0, __bf16* __restrict__ D1, __bf16* __restrict__ D2,
    int M, int N, int K,
    const float* __restrict__ bias, const float* __restrict__ res)
{
    constexpr int TM = 32 * FM, TN = 32 * FN;
    __shared__ __align__(16) __bf16 As[TM * 32];
    __shared__ __align__(16) __bf16 Bs[TN * 32];
    const int tid  = threadIdx.x;
    const int wave = tid >> 6, lane = tid & 63;
    const int q = lane >> 4, p = lane & 15;
    const int m0 = blockIdx.y * TM, n0 = blockIdx.x * TN;
    const int wm = (wave & 1) * (16 * FM);
    const int wn = (wave >> 1) * (16 * FN);
    const int lrow = lane >> 2;          // 0..15
    const int lcol = (lane & 3) * 8;     // 0,8,16,24

    f32x4 acc[FM][FN];
#pragma unroll
    for (int i = 0; i < FM; ++i)
#pragma unroll
        for (int j = 0; j < FN; ++j) {
            acc[i][j][0] = 0.f; acc[i][j][1] = 0.f;
            acc[i][j][2] = 0.f; acc[i][j][3] = 0.f;
        }

    for (int k0 = 0; k0 < K; k0 += 32) {
#pragma unroll
        for (int c = wave; c < TM / 16; c += 4)
            gl_lds16(A + (size_t)(m0 + c * 16 + lrow) * K + k0 + lcol,
                     As + c * 16 * 32);
#pragma unroll
        for (int c = wave; c < TN / 16; c += 4)
            gl_lds16(Bt + (size_t)(n0 + c * 16 + lrow) * K + k0 + lcol,
                     Bs + c * 16 * 32);
        __syncthreads();
        bf16x8 af[FM], bfr[FN];
#pragma unroll
        for (int i = 0; i < FM; ++i)
            af[i] = *(const bf16x8*)(As + (wm + i * 16 + p) * 32 + q * 8);
#pragma unroll
        for (int j = 0; j < FN; ++j)
            bfr[j] = *(const bf16x8*)(Bs + (wn + j * 16 + p) * 32 + q * 8);
#pragma unroll
        for (int i = 0; i < FM; ++i)
#pragma unroll
            for (int j = 0; j < FN; ++j)
                acc[i][j] = __builtin_amdgcn_mfma_f32_16x16x32_bf16(
                    af[i], bfr[j], acc[i][j], 0, 0, 0);
        __syncthreads();
    }

    // C/D layout: col = lane&15, row = (lane>>4)*4 + reg
#pragma unroll
    for (int i = 0; i < FM; ++i) {
#pragma unroll
        for (int j = 0; j < FN; ++j) {
            const int col = n0 + wn + j * 16 + p;
            const float bv = (EPI & 1) ? bias[col] : 0.0f;
#pragma unroll
            for (int r = 0; r < 4; ++r) {
                const int row = m0 + wm + i * 16 + q * 4 + r;
                float v = acc[i][j][r] + bv;
                if (EPI & 2) v = 0.5f * v * (1.0f + erff(v * 0.70710678118654752f));
                if (EPI & 4) v += res[(size_t)row * N + col];
                if (EPI & 16) {
                    if (col < 1024)       C0[(size_t)row * 1024 + col] = v;
                    else if (col < 2048)  D1[(size_t)row * 1024 + col - 1024] = (__bf16)v;
                    else                  D2[(size_t)row * 1024 + col - 2048] = (__bf16)v;
                } else if (EPI & 8) {
                    D1[(size_t)row * N + col] = (__bf16)v;
                } else {
                    C0[(size_t)row * N + col] = v;
                }
            }
        }
    }
}

// ---------------------------------------------------------------------------
// seg_mat[S,S,B,2] -> byte segb[b][i][j]
// ---------------------------------------------------------------------------
__global__ __launch_bounds__(256) void segpack_kernel(
    const float* __restrict__ seg_mat, unsigned char* __restrict__ segb)
{
    const int idx = blockIdx.x * 256 + threadIdx.x;
    const int b   = idx / (CS * CS);
    const int rem = idx - b * (CS * CS);
    const int i   = rem >> 10;
    const int j   = rem & (CS - 1);
    segb[idx] = seg_mat[(((size_t)i * CS + j) * CB + b) * 2 + 1] > 0.5f ? 1 : 0;
}

// ---------------------------------------------------------------------------
// ef[s][i,b,n] = sum_d (qh + r_s_bias) * seg_embed[s]
// ---------------------------------------------------------------------------
__global__ __launch_bounds__(256) void ef_kernel(
    const float* __restrict__ qh, const float* __restrict__ rsb,
    const float* __restrict__ sege, float* __restrict__ ef)
{
    const int idx = blockIdx.x * 256 + threadIdx.x;
    const int n = idx & (CN - 1);
    const float* qp = qh + (size_t)idx * CDH;
    const float* sb = rsb + n * CDH;
    const float* s0 = sege + n * CDH;
    const float* s1 = sege + (CN + n) * CDH;
    float e0 = 0.f, e1 = 0.f;
#pragma unroll
    for (int d = 0; d < CDH; ++d) {
        const float qv = qp[d] + sb[d];
        e0 = fmaf(qv, s0[d], e0);
        e1 = fmaf(qv, s1[d], e1);
    }
    ef[idx] = e0;
    ef[CS * CB * CN + idx] = e1;
}

// ---------------------------------------------------------------------------
// MFMA flash attention, bf16 K/V/Kr inputs, shuffle-based rel-shift.
// Block = (b,n, 64 q-rows). LDS 52224 B -> 3 blocks/CU.
// NOTE: default __launch_bounds__(256) only — adding ",3" capped the
// allocator at 84 arch-VGPRs and spilled accumulators to scratch (R4:
// WRITE_SIZE 8->19.5 MB, dur 91->121 us). 124 VGPRs already fits 3 blocks.
// ---------------------------------------------------------------------------
#define KSTR 40
#define VSTR 48
#define PSTR 72

__global__ __launch_bounds__(256) void attn_mfma_kernel(
    const float* __restrict__ qh, const __bf16* __restrict__ khb,
    const __bf16* __restrict__ vhb, const __bf16* __restrict__ krb,
    const float* __restrict__ efb, const unsigned char* __restrict__ segb,
    const float* __restrict__ rwb, const float* __restrict__ rrb,
    __bf16* __restrict__ vecb)
{
    __shared__ __align__(16) char smem[52224];
    __bf16* Pl  = (__bf16*)(smem);             // [4][16][PSTR]  9216 B
    __bf16* Ks  = (__bf16*)(smem + 9216);      // [2][64][KSTR] 10240 B
    __bf16* Vt  = (__bf16*)(smem + 19456);     // [2][64][VSTR] 12288 B
    __bf16* Krs = (__bf16*)(smem + 31744);     // [2][128][KSTR] 20480 B

    const int bn = blockIdx.x;
    const int b = bn >> 4, n = bn & 15;
    const int itile = (int)gridDim.y - 1 - (int)blockIdx.y;  // heavy first
    const int i0 = itile * 64;
    const int tid = threadIdx.x;
    const int w = tid >> 6;
    const int lane = tid & 63;
    const int p = lane & 15, q = lane >> 4;

    // persistent Q fragments (A-layout)
    bf16x8 qwF[2], qrF[2];
    {
        const float* qrow = qh + (((size_t)(i0 + 16 * w + p) * CB + b) * CN + n) * CDH;
        const float* rw = rwb + n * CDH;
        const float* rr = rrb + n * CDH;
#pragma unroll
        for (int ks = 0; ks < 2; ++ks)
#pragma unroll
            for (int t = 0; t < 8; ++t) {
                const int d = ks * 32 + q * 8 + t;
                const float v = qrow[d];
                qwF[ks][t] = (__bf16)(v + rw[d]);
                qrF[ks][t] = (__bf16)(v + rr[d]);
            }
    }
    float ef0r[4], ef1r[4];
#pragma unroll
    for (int r = 0; r < 4; ++r) {
        const size_t e = ((size_t)(i0 + 16 * w + 4 * q + r) * CB + b) * CN + n;
        ef0r[r] = efb[e];
        ef1r[r] = efb[(size_t)CS * CB * CN + e];
    }

    f32x4 opv[4];
    float mrow[4], lrow[4];
#pragma unroll
    for (int nf = 0; nf < 4; ++nf) { opv[nf][0]=0.f; opv[nf][1]=0.f; opv[nf][2]=0.f; opv[nf][3]=0.f; }
#pragma unroll
    for (int r = 0; r < 4; ++r) { mrow[r] = -3.0e38f; lrow[r] = 0.f; }

    const int ntile = itile + 1;
    const unsigned char* sb = segb + (size_t)b * CS * CS;
    const int wbase = 48 - 16 * w;

    for (int jt = 0; jt < ntile; ++jt) {
        const int j0 = jt * 64;
        const int gs = j0 + CS - i0 - 63;      // in [1, 961]

        // ---- stage K (bf16), Kr band, V^T ----
        {
            const __bf16* kbase = khb + ((size_t)j0 * CB + b) * CN * CDH + n * CDH;
#pragma unroll
            for (int it = 0; it < 2; ++it) {
                const int idx = it * 256 + tid;
                const int row = idx >> 3, o = idx & 7;
                const uint4 v = *(const uint4*)(kbase + (size_t)row * (CB*CN*CDH) + o * 8);
                *(uint4*)(Ks + (o >> 2) * (64 * KSTR) + row * KSTR + (o & 3) * 8) = v;
            }
            const __bf16* krbase = krb + ((size_t)gs * CB + b) * CN * CDH + n * CDH;
#pragma unroll
            for (int it = 0; it < 4; ++it) {
                const int idx = it * 256 + tid;
                const int row = idx >> 3, o = idx & 7;
                const uint4 v = *(const uint4*)(krbase + (size_t)row * (CB*CN*CDH) + o * 8);
                *(uint4*)(Krs + (o >> 2) * (128 * KSTR) + row * KSTR + (o & 3) * 8) = v;
            }
            const int jp = tid >> 3, o = tid & 7;
            const int j = jp * 2;
            const __bf16* vbase = vhb + ((size_t)(j0 + j) * CB + b) * CN * CDH + n * CDH + o * 8;
            union { uint4 u; unsigned short s[8]; } a0, a1;
            a0.u = *(const uint4*)vbase;
            a1.u = *(const uint4*)(vbase + CB*CN*CDH);
            const int jh = j >> 5, jc = j & 31;
#pragma unroll
            for (int tt = 0; tt < 8; ++tt) {
                const int t = (tt + o) & 7;
                const unsigned int dw = (unsigned int)a0.s[t] | ((unsigned int)a1.s[t] << 16);
                *(unsigned int*)(Vt + jh * (64 * VSTR) + (o * 8 + t) * VSTR + jc) = dw;
            }
        }
        __syncthreads();

        // ---- ac (8 MFMA) + bd raw band (10 MFMA) ----
        f32x4 ac[4], rawacc[5];
#pragma unroll
        for (int nf = 0; nf < 4; ++nf) { ac[nf][0]=0.f; ac[nf][1]=0.f; ac[nf][2]=0.f; ac[nf][3]=0.f; }
#pragma unroll
        for (int t = 0; t < 5; ++t) { rawacc[t][0]=0.f; rawacc[t][1]=0.f; rawacc[t][2]=0.f; rawacc[t][3]=0.f; }
#pragma unroll
        for (int ks = 0; ks < 2; ++ks) {
#pragma unroll
            for (int nf = 0; nf < 4; ++nf) {
                const bf16x8 bf = *(const bf16x8*)(Ks + ks * (64 * KSTR) + (nf * 16 + p) * KSTR + q * 8);
                ac[nf] = __builtin_amdgcn_mfma_f32_16x16x32_bf16(qwF[ks], bf, ac[nf], 0, 0, 0);
            }
#pragma unroll
            for (int t = 0; t < 5; ++t) {
                const bf16x8 bf = *(const bf16x8*)(Krs + ks * (128 * KSTR) + (wbase + t * 16 + p) * KSTR + q * 8);
                rawacc[t] = __builtin_amdgcn_mfma_f32_16x16x32_bf16(qrF[ks], bf, rawacc[t], 0, 0, 0);
            }
        }

        // ---- rel-shift extraction via shuffles ----
        // bd(rl=4q+r, jj=nf*16+p) = band[rl][nf*16 + p + 15 - rl]
        float bd[4][4];
#pragma unroll
        for (int r = 0; r < 4; ++r) {
            const int rl = 4 * q + r;
            const int delta = p + 15 - rl;             // 0..30
            const int srcl = (q << 4) | (delta & 15);
            float sh[5];
#pragma unroll
            for (int t = 0; t < 5; ++t) sh[t] = __shfl(rawacc[t][r], srcl);
            const int hi = delta >> 4;
#pragma unroll
            for (int nf = 0; nf < 4; ++nf)
                bd[nf][r] = hi ? sh[nf + 1] : sh[nf];
        }

        // ---- scores + online softmax ----
        const bool diag = (jt == ntile - 1);
        float sc[4][4];
#pragma unroll
        for (int nf = 0; nf < 4; ++nf) {
            const int jj = nf * 16 + p;
#pragma unroll
            for (int r = 0; r < 4; ++r) {
                const int rl = 4 * q + r;
                const int ii = i0 + 16 * w + rl;
                const float e = sb[(size_t)ii * CS + (j0 + jj)] ? ef1r[r] : ef0r[r];
                float s = (ac[nf][r] + bd[nf][r] + e) * 0.125f;
                if (diag && jj > 16 * w + rl) s = -3.0e38f;
                sc[nf][r] = s;
            }
        }
        float al[4], ls[4];
#pragma unroll
        for (int r = 0; r < 4; ++r) {
            float m = fmaxf(fmaxf(sc[0][r], sc[1][r]), fmaxf(sc[2][r], sc[3][r]));
#pragma unroll
            for (int off = 1; off < 16; off <<= 1) m = fmaxf(m, __shfl_xor(m, off));
            const float mn = fmaxf(mrow[r], m);
            al[r] = __expf(mrow[r] - mn);
            mrow[r] = mn;
            ls[r] = 0.f;
        }
#pragma unroll
        for (int nf = 0; nf < 4; ++nf)
#pragma unroll
            for (int r = 0; r < 4; ++r) {
                const float pv = __expf(sc[nf][r] - mrow[r]);
                sc[nf][r] = pv;
                ls[r] += pv;
            }
#pragma unroll
        for (int r = 0; r < 4; ++r) {
            float s = ls[r];
#pragma unroll
            for (int off = 1; off < 16; off <<= 1) s += __shfl_xor(s, off);
            lrow[r] = lrow[r] * al[r] + s;
#pragma unroll
            for (int nf = 0; nf < 4; ++nf) opv[nf][r] *= al[r];
        }

        // ---- P C-layout -> LDS -> A-layout, then PV ----
        __bf16* pw = Pl + w * (16 * PSTR);
#pragma unroll
        for (int nf = 0; nf < 4; ++nf)
#pragma unroll
            for (int r = 0; r < 4; ++r)
                pw[(4 * q + r) * PSTR + nf * 16 + p] = (__bf16)sc[nf][r];

#pragma unroll
        for (int ks = 0; ks < 2; ++ks) {
            const bf16x8 pf = *(const bf16x8*)(pw + p * PSTR + ks * 32 + q * 8);
#pragma unroll
            for (int nf = 0; nf < 4; ++nf) {
                const bf16x8 vf = *(const bf16x8*)(Vt + ks * (64 * VSTR) + (nf * 16 + p) * VSTR + q * 8);
                opv[nf] = __builtin_amdgcn_mfma_f32_16x16x32_bf16(pf, vf, opv[nf], 0, 0, 0);
            }
        }
        __syncthreads();
    }

    // ---- epilogue: normalize, write vec bf16 ----
#pragma unroll
    for (int r = 0; r < 4; ++r) {
        const float ri = 1.0f / lrow[r];
        const int i = i0 + 16 * w + 4 * q + r;
        __bf16* op = vecb + (((size_t)i * CB + b) * CN + n) * CDH;
#pragma unroll
        for (int nf = 0; nf < 4; ++nf)
            op[nf * 16 + p] = (__bf16)(opv[nf][r] * ri);
    }
}

// ---------------------------------------------------------------------------
// LayerNorm over D=1024, optional bf16 shadow output
// ---------------------------------------------------------------------------
__global__ __launch_bounds__(256) void ln_kernel(
    const float* __restrict__ x, float* __restrict__ y,
    unsigned short* __restrict__ yb,
    const float* __restrict__ g, const float* __restrict__ bb)
{
    __shared__ float red[8];
    const int row = blockIdx.x;
    const int tid = threadIdx.x;
    const float4 v = ((const float4*)(x + (size_t)row * CD))[tid];
    float s = v.x + v.y + v.z + v.w;
#pragma unroll
    for (int off = 32; off; off >>= 1) s += __shfl_xor(s, off, 64);
    if ((tid & 63) == 0) red[tid >> 6] = s;
    __syncthreads();
    const float mean = (red[0] + red[1] + red[2] + red[3]) * (1.f / CD);
    const float d0 = v.x - mean, d1 = v.y - mean, d2 = v.z - mean, d3 = v.w - mean;
    float ss = d0 * d0 + d1 * d1 + d2 * d2 + d3 * d3;
#pragma unroll
    for (int off = 32; off; off >>= 1) ss += __shfl_xor(ss, off, 64);
    if ((tid & 63) == 0) red[4 + (tid >> 6)] = ss;
    __syncthreads();
    const float var  = (red[4] + red[5] + red[6] + red[7]) * (1.f / CD);
    const float rstd = rsqrtf(var + 1e-12f);
    const float4 gv = ((const float4*)g)[tid];
    const float4 bv = ((const float4*)bb)[tid];
    float4 o;
    o.x = d0 * rstd * gv.x + bv.x;
    o.y = d1 * rstd * gv.y + bv.y;
    o.z = d2 * rstd * gv.z + bv.z;
    o.w = d3 * rstd * gv.w + bv.w;
    ((float4*)(y + (size_t)row * CD))[tid] = o;
    if (yb) {
        ushort4 ob;
        ob.x = f2b(o.x); ob.y = f2b(o.y); ob.z = f2b(o.z); ob.w = f2b(o.w);
        ((ushort4*)(yb + (size_t)row * CD))[tid] = ob;
    }
}

// ---------------------------------------------------------------------------
// Workspace layout (MiB, total 74.25 proven):
//  [0,8) cur f32 | [8,16) qh f32 | [16,20) khb bf16 | [20,24) vhb bf16
//  [24,32) krb bf16 | [32,40) wbuf bf16 | [40,44) vec_b bf16 | [44,52) ax f32
//  [52,60) xb f32 | [60,64) cur_b/xb_b bf16 (time-shared) | [64,72) pos_b bf16
//  [72,72.25) efb | [72.25,74.25) segb
//  ffb bf16 [8,24) aliases qh/khb/vhb (dead at FFN time)
// ---------------------------------------------------------------------------
extern "C" void kernel_launch(void* const* d_in, const int* in_sizes, int n_in,
                              void* d_out, int out_size, void* d_ws, size_t ws_size,
                              hipStream_t stream)
{
    const float* h       = (const float*)d_in[0];
    const float* pos_emb = (const float*)d_in[1];
    const float* seg_mat = (const float*)d_in[3];
    const float* Wq  = (const float*)d_in[4];
    const float* Wk  = (const float*)d_in[5];
    const float* Wv  = (const float*)d_in[6];
    const float* Wo  = (const float*)d_in[7];
    const float* Wr  = (const float*)d_in[8];
    const float* rwb = (const float*)d_in[9];
    const float* rrb = (const float*)d_in[10];
    const float* rsb = (const float*)d_in[11];
    const float* sege = (const float*)d_in[12];
    const float* ln1g = (const float*)d_in[13];
    const float* ln1b = (const float*)d_in[14];
    const float* fw1  = (const float*)d_in[15];
    const float* fb1  = (const float*)d_in[16];
    const float* fw2  = (const float*)d_in[17];
    const float* fb2  = (const float*)d_in[18];
    const float* ln2g = (const float*)d_in[19];
    const float* ln2b = (const float*)d_in[20];
    float* out = (float*)d_out;

    char* base = (char*)d_ws;
    const size_t MB = 1u << 20;
    float* cur  = (float*)(base + 0 * MB);
    float* qh   = (float*)(base + 8 * MB);
    __bf16* khb = (__bf16*)(base + 16 * MB);
    __bf16* vhb = (__bf16*)(base + 20 * MB);
    __bf16* krb = (__bf16*)(base + 24 * MB);
    unsigned short* wbuf = (unsigned short*)(base + 32 * MB);
    __bf16* vec_b = (__bf16*)(base + 40 * MB);
    float* ax   = (float*)(base + 44 * MB);
    float* xb   = (float*)(base + 52 * MB);
    unsigned short* curxb_b = (unsigned short*)(base + 60 * MB);  // cur_b / xb_b
    unsigned short* pos_b = (unsigned short*)(base + 64 * MB);
    float* efb  = (float*)(base + 72 * MB);
    unsigned char* segb = (unsigned char*)(base + 72 * MB + (1u << 18));
    __bf16* ffb = (__bf16*)(base + 8 * MB);   // aliases qh/khb/vhb

    hipMemcpyAsync(cur, h, (size_t)CS * CB * CD * sizeof(float),
                   hipMemcpyDeviceToDevice, stream);
    convert_f2b_kernel<<<(CS * CB * CD / 4) / 256, 256, 0, stream>>>(
        h, curxb_b, CS * CB * CD / 4);
    convert_f2b_kernel<<<(CR * CB * CD / 4) / 256, 256, 0, stream>>>(
        pos_emb, pos_b, CR * CB * CD / 4);
    segpack_kernel<<<(CS * CS * CB) / 256, 256, 0, stream>>>(seg_mat, segb);

    const int MQ = CS * CB;   // 2048
    for (int l = 0; l < CL; ++l) {
        const size_t wOff = (size_t)l * CD * CN * CDH;
        // fused QKV: Bt = [WqT ; WkT ; WvT], outputs qh f32 + khb/vhb bf16
        transpose_f2b_kernel<<<dim3(32, 32), 256, 0, stream>>>(Wq + wOff, wbuf, CD, CD);
        transpose_f2b_kernel<<<dim3(32, 32), 256, 0, stream>>>(Wk + wOff, wbuf + 1024 * 1024, CD, CD);
        transpose_f2b_kernel<<<dim3(32, 32), 256, 0, stream>>>(Wv + wOff, wbuf + 2 * 1024 * 1024, CD, CD);
        mgemm<4, 4, 16><<<dim3(3072 / 128, MQ / 128), 256, 0, stream>>>(
            (const __bf16*)curxb_b, (const __bf16*)wbuf, qh, khb, vhb,
            MQ, 3072, CD, nullptr, nullptr);
        // R projection -> krb bf16
        transpose_f2b_kernel<<<dim3(32, 32), 256, 0, stream>>>(Wr + wOff, wbuf, CD, CD);
        mgemm<4, 4, 8><<<dim3(1024 / 128, (CR * CB) / 128), 256, 0, stream>>>(
            (const __bf16*)pos_b, (const __bf16*)wbuf, nullptr, krb, nullptr,
            CR * CB, CD, CD, nullptr, nullptr);
        ef_kernel<<<(CS * CB * CN) / 256, 256, 0, stream>>>(
            qh, rsb + (size_t)l * CN * CDH, sege + (size_t)l * 2 * CN * CDH, efb);
        attn_mfma_kernel<<<dim3(CB * CN, CS / 64), 256, 0, stream>>>(
            qh, khb, vhb, krb, efb, segb,
            rwb + (size_t)l * CN * CDH, rrb + (size_t)l * CN * CDH, vec_b);
        // Wo projection + residual (Wo already [h][n*d] = Bt layout)
        convert_f2b_kernel<<<(CD * CD / 4) / 256, 256, 0, stream>>>(Wo + wOff, wbuf, CD * CD / 4);
        mgemm<2, 4, 4><<<dim3(1024 / 128, MQ / 64), 256, 0, stream>>>(
            vec_b, (const __bf16*)wbuf, ax, nullptr, nullptr,
            MQ, CD, CD, nullptr, cur);
        ln_kernel<<<MQ, 256, 0, stream>>>(ax, xb, curxb_b, ln1g + l * CD, ln1b + l * CD);
        // FFN
        transpose_f2b_kernel<<<dim3(CDI / 32, CD / 32), 256, 0, stream>>>(
            fw1 + (size_t)l * CD * CDI, wbuf, CD, CDI);
        mgemm<4, 4, 1 | 2 | 8><<<dim3(CDI / 128, MQ / 128), 256, 0, stream>>>(
            (const __bf16*)curxb_b, (const __bf16*)wbuf, nullptr, ffb, nullptr,
            MQ, CDI, CD, fb1 + l * CDI, nullptr);
        transpose_f2b_kernel<<<dim3(CD / 32, CDI / 32), 256, 0, stream>>>(
            fw2 + (size_t)l * CDI * CD, wbuf, CDI, CD);
        mgemm<2, 4, 1 | 4><<<dim3(CD / 128, MQ / 64), 256, 0, stream>>>(
            ffb, (const __bf16*)wbuf, ax, nullptr, nullptr,
            MQ, CD, CDI, fb2 + l * CD, xb);
        if (l == CL - 1)
            ln_kernel<<<MQ, 256, 0, stream>>>(ax, out, nullptr, ln2g + l * CD, ln2b + l * CD);
        else
            ln_kernel<<<MQ, 256, 0, stream>>>(ax, cur, curxb_b, ln2g + l * CD, ln2b + l * CD);
    }
}

// Round 6
// 802.517 us; speedup vs baseline: 1.0881x; 1.0306x over previous
//
#include <hip/hip_runtime.h>
#include <hip/hip_bf16.h>
#include <math.h>

#define CS  1024
#define CB  2
#define CD  1024
#define CN  16
#define CDH 64
#define CDI 4096
#define CR  2048
#define CL  2

typedef __bf16 bf16x8 __attribute__((ext_vector_type(8)));
typedef float  f32x4  __attribute__((ext_vector_type(4)));

__device__ __forceinline__ unsigned short f2b(float f) {
    unsigned int u = __float_as_uint(f);
    u += 0x7FFF + ((u >> 16) & 1);          // RNE
    return (unsigned short)(u >> 16);
}

// async global->LDS 16B per lane: lane i lands at ldsbase + i*16 (wave-uniform base)
__device__ __forceinline__ void gl_lds16(const void* g, void* l) {
    __builtin_amdgcn_global_load_lds(
        (const __attribute__((address_space(1))) unsigned int*)g,
        (__attribute__((address_space(3))) unsigned int*)l, 16, 0, 0);
}

// ---------------------------------------------------------------------------
// flat fp32 -> bf16 convert (x4)
// ---------------------------------------------------------------------------
__global__ __launch_bounds__(256) void convert_f2b_kernel(
    const float* __restrict__ in, unsigned short* __restrict__ out, int n4)
{
    const int i = blockIdx.x * 256 + threadIdx.x;
    if (i >= n4) return;
    const float4 v = ((const float4*)in)[i];
    ushort4 o;
    o.x = f2b(v.x); o.y = f2b(v.y); o.z = f2b(v.z); o.w = f2b(v.w);
    ((ushort4*)out)[i] = o;
}

// ---------------------------------------------------------------------------
// fp32 [K,N] -> bf16 [N,K] transpose-convert
// ---------------------------------------------------------------------------
__global__ __launch_bounds__(256) void transpose_f2b_kernel(
    const float* __restrict__ in, unsigned short* __restrict__ out, int K, int N)
{
    __shared__ unsigned short t[32][33];
    const int k0 = blockIdx.y * 32, n0 = blockIdx.x * 32;
    const int c = threadIdx.x & 31, r0 = threadIdx.x >> 5;
    for (int r = r0; r < 32; r += 8)
        t[r][c] = f2b(in[(size_t)(k0 + r) * N + n0 + c]);
    __syncthreads();
    for (int r = r0; r < 32; r += 8)
        out[(size_t)(n0 + r) * K + k0 + c] = t[c][r];
}

// ---------------------------------------------------------------------------
// m97-style bf16 MFMA GEMM: C = A[M,K] @ Bt[N,K]^T, global_load_lds staging.
// LDS tiles unpadded [rows][32] bf16. 4 waves 2x2.
// EPI bits: 1=bias 2=gelu 4=res 8=bf16 out(D1) 16=split3 (C0 fp32|D1|D2 bf16)
// ---------------------------------------------------------------------------
template<int FM, int FN, int EPI>
__global__ __launch_bounds__(256) void mgemm(
    const __bf16* __restrict__ A, const __bf16* __restrict__ Bt,
    float* __restrict__ C0, __bf16* __restrict__ D1, __bf16* __restrict__ D2,
    int M, int N, int K,
    const float* __restrict__ bias, const float* __restrict__ res)
{
    constexpr int TM = 32 * FM, TN = 32 * FN;
    __shared__ __align__(16) __bf16 As[TM * 32];
    __shared__ __align__(16) __bf16 Bs[TN * 32];
    const int tid  = threadIdx.x;
    const int wave = tid >> 6, lane = tid & 63;
    const int q = lane >> 4, p = lane & 15;
    const int m0 = blockIdx.y * TM, n0 = blockIdx.x * TN;
    const int wm = (wave & 1) * (16 * FM);
    const int wn = (wave >> 1) * (16 * FN);
    const int lrow = lane >> 2;          // 0..15
    const int lcol = (lane & 3) * 8;     // 0,8,16,24

    f32x4 acc[FM][FN];
#pragma unroll
    for (int i = 0; i < FM; ++i)
#pragma unroll
        for (int j = 0; j < FN; ++j) {
            acc[i][j][0] = 0.f; acc[i][j][1] = 0.f;
            acc[i][j][2] = 0.f; acc[i][j][3] = 0.f;
        }

    for (int k0 = 0; k0 < K; k0 += 32) {
#pragma unroll
        for (int c = wave; c < TM / 16; c += 4)
            gl_lds16(A + (size_t)(m0 + c * 16 + lrow) * K + k0 + lcol,
                     As + c * 16 * 32);
#pragma unroll
        for (int c = wave; c < TN / 16; c += 4)
            gl_lds16(Bt + (size_t)(n0 + c * 16 + lrow) * K + k0 + lcol,
                     Bs + c * 16 * 32);
        __syncthreads();
        bf16x8 af[FM], bfr[FN];
#pragma unroll
        for (int i = 0; i < FM; ++i)
            af[i] = *(const bf16x8*)(As + (wm + i * 16 + p) * 32 + q * 8);
#pragma unroll
        for (int j = 0; j < FN; ++j)
            bfr[j] = *(const bf16x8*)(Bs + (wn + j * 16 + p) * 32 + q * 8);
#pragma unroll
        for (int i = 0; i < FM; ++i)
#pragma unroll
            for (int j = 0; j < FN; ++j)
                acc[i][j] = __builtin_amdgcn_mfma_f32_16x16x32_bf16(
                    af[i], bfr[j], acc[i][j], 0, 0, 0);
        __syncthreads();
    }

    // C/D layout: col = lane&15, row = (lane>>4)*4 + reg
#pragma unroll
    for (int i = 0; i < FM; ++i) {
#pragma unroll
        for (int j = 0; j < FN; ++j) {
            const int col = n0 + wn + j * 16 + p;
            const float bv = (EPI & 1) ? bias[col] : 0.0f;
#pragma unroll
            for (int r = 0; r < 4; ++r) {
                const int row = m0 + wm + i * 16 + q * 4 + r;
                float v = acc[i][j][r] + bv;
                if (EPI & 2) v = 0.5f * v * (1.0f + erff(v * 0.70710678118654752f));
                if (EPI & 4) v += res[(size_t)row * N + col];
                if (EPI & 16) {
                    if (col < 1024)       C0[(size_t)row * 1024 + col] = v;
                    else if (col < 2048)  D1[(size_t)row * 1024 + col - 1024] = (__bf16)v;
                    else                  D2[(size_t)row * 1024 + col - 2048] = (__bf16)v;
                } else if (EPI & 8) {
                    D1[(size_t)row * N + col] = (__bf16)v;
                } else {
                    C0[(size_t)row * N + col] = v;
                }
            }
        }
    }
}

// ---------------------------------------------------------------------------
// seg_mat[S,S,B,2] -> u64 bitmask segm[b][i][j/64], bit jj = (seg differs)
// ---------------------------------------------------------------------------
__global__ __launch_bounds__(256) void segpack_bits_kernel(
    const float* __restrict__ seg_mat, unsigned long long* __restrict__ segm)
{
    const int idx = blockIdx.x * 256 + threadIdx.x;   // < B*S*16 = 32768
    const int b   = idx / (CS * 16);
    const int rem = idx - b * (CS * 16);
    const int i   = rem >> 4;
    const int wd  = rem & 15;
    unsigned long long m = 0;
#pragma unroll 8
    for (int jj = 0; jj < 64; ++jj) {
        const float f = seg_mat[(((size_t)i * CS + (wd * 64 + jj)) * CB + b) * 2 + 1];
        m |= (unsigned long long)(f > 0.5f) << jj;
    }
    segm[idx] = m;
}

// ---------------------------------------------------------------------------
// ef[s][i,b,n] = sum_d (qh + r_s_bias) * seg_embed[s]
// ---------------------------------------------------------------------------
__global__ __launch_bounds__(256) void ef_kernel(
    const float* __restrict__ qh, const float* __restrict__ rsb,
    const float* __restrict__ sege, float* __restrict__ ef)
{
    const int idx = blockIdx.x * 256 + threadIdx.x;
    const int n = idx & (CN - 1);
    const float* qp = qh + (size_t)idx * CDH;
    const float* sb = rsb + n * CDH;
    const float* s0 = sege + n * CDH;
    const float* s1 = sege + (CN + n) * CDH;
    float e0 = 0.f, e1 = 0.f;
#pragma unroll
    for (int d = 0; d < CDH; ++d) {
        const float qv = qp[d] + sb[d];
        e0 = fmaf(qv, s0[d], e0);
        e1 = fmaf(qv, s1[d], e1);
    }
    ef[idx] = e0;
    ef[CS * CB * CN + idx] = e1;
}

// ---------------------------------------------------------------------------
// MFMA flash attention, bf16 K/V/Kr inputs, gl_lds16 K/Kr staging,
// shuffle rel-shift, bitmask segment select, Q pre-scaled by 1/8.
// Block = (b,n, 64 q-rows). LDS 46080 B -> 3 blocks/CU.
// Default __launch_bounds__(256) only (R4: ",3" caused spills).
// ---------------------------------------------------------------------------
#define VSTR 48
#define PSTR 72

__global__ __launch_bounds__(256) void attn_mfma_kernel(
    const float* __restrict__ qh, const __bf16* __restrict__ khb,
    const __bf16* __restrict__ vhb, const __bf16* __restrict__ krb,
    const float* __restrict__ efb, const unsigned long long* __restrict__ segm,
    const float* __restrict__ rwb, const float* __restrict__ rrb,
    __bf16* __restrict__ vecb)
{
    __shared__ __align__(16) char smem[46080];
    __bf16* Pl  = (__bf16*)(smem);             // [4][16][PSTR]  9216 B
    __bf16* Ks  = (__bf16*)(smem + 9216);      // [2][64][32]    8192 B
    __bf16* Vt  = (__bf16*)(smem + 17408);     // [2][64][VSTR] 12288 B
    __bf16* Krs = (__bf16*)(smem + 29696);     // [2][128][32]  16384 B

    const int bn = blockIdx.x;
    const int b = bn >> 4, n = bn & 15;
    const int itile = (int)gridDim.y - 1 - (int)blockIdx.y;  // heavy first
    const int i0 = itile * 64;
    const int tid = threadIdx.x;
    const int w = tid >> 6;
    const int lane = tid & 63;
    const int p = lane & 15, q = lane >> 4;
    const int lrow = lane >> 2;          // 0..15
    const int lcol = (lane & 3) * 8;     // 0,8,16,24
    const size_t rstride = (size_t)CB * CN * CDH;   // row stride in khb/vhb/krb

    // persistent Q fragments (A-layout), pre-scaled by 1/8 (exact)
    bf16x8 qwF[2], qrF[2];
    {
        const float* qrow = qh + (((size_t)(i0 + 16 * w + p) * CB + b) * CN + n) * CDH;
        const float* rw = rwb + n * CDH;
        const float* rr = rrb + n * CDH;
#pragma unroll
        for (int ks = 0; ks < 2; ++ks)
#pragma unroll
            for (int t = 0; t < 8; ++t) {
                const int d = ks * 32 + q * 8 + t;
                const float v = qrow[d];
                qwF[ks][t] = (__bf16)((v + rw[d]) * 0.125f);
                qrF[ks][t] = (__bf16)((v + rr[d]) * 0.125f);
            }
    }
    // ef pre-scaled: score adds ef0 + efd*bit
    float ef0r[4], efd[4];
#pragma unroll
    for (int r = 0; r < 4; ++r) {
        const size_t e = ((size_t)(i0 + 16 * w + 4 * q + r) * CB + b) * CN + n;
        const float e0 = efb[e];
        ef0r[r] = e0 * 0.125f;
        efd[r]  = (efb[(size_t)CS * CB * CN + e] - e0) * 0.125f;
    }

    f32x4 opv[4];
    float mrow[4], lrow4[4];
#pragma unroll
    for (int nf = 0; nf < 4; ++nf) { opv[nf][0]=0.f; opv[nf][1]=0.f; opv[nf][2]=0.f; opv[nf][3]=0.f; }
#pragma unroll
    for (int r = 0; r < 4; ++r) { mrow[r] = -3.0e38f; lrow4[r] = 0.f; }

    const int ntile = itile + 1;
    const unsigned long long* sgm = segm + (size_t)b * CS * 16;
    const int wbase = 48 - 16 * w;

    for (int jt = 0; jt < ntile; ++jt) {
        const int j0 = jt * 64;
        const int gs = j0 + CS - i0 - 63;      // in [1, 961]

        // ---- segment mask words (independent loads, overlap with staging)
        unsigned long long segw[4];
        const int wi = j0 >> 6;
#pragma unroll
        for (int r = 0; r < 4; ++r)
            segw[r] = sgm[(size_t)(i0 + 16 * w + 4 * q + r) * 16 + wi];

        // ---- stage K (8 calls) and Kr (16 calls) via global_load_lds ----
#pragma unroll
        for (int c = w; c < 8; c += 4) {
            const int h = c & 1, grp = c >> 1;
            gl_lds16(khb + (size_t)(j0 + grp * 16 + lrow) * rstride
                         + (size_t)((b * CN + n) * CDH) + h * 32 + lcol,
                     Ks + h * (64 * 32) + grp * (16 * 32));
        }
#pragma unroll
        for (int c = w; c < 16; c += 4) {
            const int h = c & 1, grp = c >> 1;
            gl_lds16(krb + (size_t)(gs + grp * 16 + lrow) * rstride
                         + (size_t)((b * CN + n) * CDH) + h * 32 + lcol,
                     Krs + h * (128 * 32) + grp * (16 * 32));
        }
        {   // V transpose staging (manual, 2 uint4 loads + 8 u32 LDS writes)
            const int jp = tid >> 3, o = tid & 7;
            const int j = jp * 2;
            const __bf16* vbase = vhb + (size_t)(j0 + j) * rstride
                                + (size_t)((b * CN + n) * CDH) + o * 8;
            union { uint4 u; unsigned short s[8]; } a0, a1;
            a0.u = *(const uint4*)vbase;
            a1.u = *(const uint4*)(vbase + rstride);
            const int jh = j >> 5, jc = j & 31;
#pragma unroll
            for (int tt = 0; tt < 8; ++tt) {
                const int t = (tt + o) & 7;
                const unsigned int dw = (unsigned int)a0.s[t] | ((unsigned int)a1.s[t] << 16);
                *(unsigned int*)(Vt + jh * (64 * VSTR) + (o * 8 + t) * VSTR + jc) = dw;
            }
        }
        __syncthreads();

        // ---- ac (8 MFMA) + bd raw band (10 MFMA) ----
        f32x4 ac[4], rawacc[5];
#pragma unroll
        for (int nf = 0; nf < 4; ++nf) { ac[nf][0]=0.f; ac[nf][1]=0.f; ac[nf][2]=0.f; ac[nf][3]=0.f; }
#pragma unroll
        for (int t = 0; t < 5; ++t) { rawacc[t][0]=0.f; rawacc[t][1]=0.f; rawacc[t][2]=0.f; rawacc[t][3]=0.f; }
#pragma unroll
        for (int ks = 0; ks < 2; ++ks) {
#pragma unroll
            for (int nf = 0; nf < 4; ++nf) {
                const bf16x8 bf = *(const bf16x8*)(Ks + ks * (64 * 32) + (nf * 16 + p) * 32 + q * 8);
                ac[nf] = __builtin_amdgcn_mfma_f32_16x16x32_bf16(qwF[ks], bf, ac[nf], 0, 0, 0);
            }
#pragma unroll
            for (int t = 0; t < 5; ++t) {
                const bf16x8 bf = *(const bf16x8*)(Krs + ks * (128 * 32) + (wbase + t * 16 + p) * 32 + q * 8);
                rawacc[t] = __builtin_amdgcn_mfma_f32_16x16x32_bf16(qrF[ks], bf, rawacc[t], 0, 0, 0);
            }
        }

        // ---- rel-shift extraction via shuffles ----
        // bd(rl=4q+r, jj=nf*16+p) = band[rl][nf*16 + p + 15 - rl]
        float bd[4][4];
#pragma unroll
        for (int r = 0; r < 4; ++r) {
            const int rl = 4 * q + r;
            const int delta = p + 15 - rl;             // 0..30
            const int srcl = (q << 4) | (delta & 15);
            float sh[5];
#pragma unroll
            for (int t = 0; t < 5; ++t) sh[t] = __shfl(rawacc[t][r], srcl);
            const int hi = delta >> 4;
#pragma unroll
            for (int nf = 0; nf < 4; ++nf)
                bd[nf][r] = hi ? sh[nf + 1] : sh[nf];
        }

        // ---- scores + online softmax (ac/bd already scaled via Q) ----
        const bool diag = (jt == ntile - 1);
        float sc[4][4];
#pragma unroll
        for (int nf = 0; nf < 4; ++nf) {
            const int jj = nf * 16 + p;
#pragma unroll
            for (int r = 0; r < 4; ++r) {
                const int rl = 4 * q + r;
                const float bitf = (float)((segw[r] >> jj) & 1ULL);
                float s = ac[nf][r] + bd[nf][r] + fmaf(efd[r], bitf, ef0r[r]);
                if (diag && jj > 16 * w + rl) s = -3.0e38f;
                sc[nf][r] = s;
            }
        }
        float al[4], ls[4];
#pragma unroll
        for (int r = 0; r < 4; ++r) {
            float m = fmaxf(fmaxf(sc[0][r], sc[1][r]), fmaxf(sc[2][r], sc[3][r]));
#pragma unroll
            for (int off = 1; off < 16; off <<= 1) m = fmaxf(m, __shfl_xor(m, off));
            const float mn = fmaxf(mrow[r], m);
            al[r] = __expf(mrow[r] - mn);
            mrow[r] = mn;
            ls[r] = 0.f;
        }
#pragma unroll
        for (int nf = 0; nf < 4; ++nf)
#pragma unroll
            for (int r = 0; r < 4; ++r) {
                const float pv = __expf(sc[nf][r] - mrow[r]);
                sc[nf][r] = pv;
                ls[r] += pv;
            }
#pragma unroll
        for (int r = 0; r < 4; ++r) {
            float s = ls[r];
#pragma unroll
            for (int off = 1; off < 16; off <<= 1) s += __shfl_xor(s, off);
            lrow4[r] = lrow4[r] * al[r] + s;
#pragma unroll
            for (int nf = 0; nf < 4; ++nf) opv[nf][r] *= al[r];
        }

        // ---- P C-layout -> LDS -> A-layout, then PV ----
        __bf16* pw = Pl + w * (16 * PSTR);
#pragma unroll
        for (int nf = 0; nf < 4; ++nf)
#pragma unroll
            for (int r = 0; r < 4; ++r)
                pw[(4 * q + r) * PSTR + nf * 16 + p] = (__bf16)sc[nf][r];

#pragma unroll
        for (int ks = 0; ks < 2; ++ks) {
            const bf16x8 pf = *(const bf16x8*)(pw + p * PSTR + ks * 32 + q * 8);
#pragma unroll
            for (int nf = 0; nf < 4; ++nf) {
                const bf16x8 vf = *(const bf16x8*)(Vt + ks * (64 * VSTR) + (nf * 16 + p) * VSTR + q * 8);
                opv[nf] = __builtin_amdgcn_mfma_f32_16x16x32_bf16(pf, vf, opv[nf], 0, 0, 0);
            }
        }
        __syncthreads();
    }

    // ---- epilogue: normalize, write vec bf16 ----
#pragma unroll
    for (int r = 0; r < 4; ++r) {
        const float ri = 1.0f / lrow4[r];
        const int i = i0 + 16 * w + 4 * q + r;
        __bf16* op = vecb + (((size_t)i * CB + b) * CN + n) * CDH;
#pragma unroll
        for (int nf = 0; nf < 4; ++nf)
            op[nf * 16 + p] = (__bf16)(opv[nf][r] * ri);
    }
}

// ---------------------------------------------------------------------------
// LayerNorm over D=1024, optional bf16 shadow output
// ---------------------------------------------------------------------------
__global__ __launch_bounds__(256) void ln_kernel(
    const float* __restrict__ x, float* __restrict__ y,
    unsigned short* __restrict__ yb,
    const float* __restrict__ g, const float* __restrict__ bb)
{
    __shared__ float red[8];
    const int row = blockIdx.x;
    const int tid = threadIdx.x;
    const float4 v = ((const float4*)(x + (size_t)row * CD))[tid];
    float s = v.x + v.y + v.z + v.w;
#pragma unroll
    for (int off = 32; off; off >>= 1) s += __shfl_xor(s, off, 64);
    if ((tid & 63) == 0) red[tid >> 6] = s;
    __syncthreads();
    const float mean = (red[0] + red[1] + red[2] + red[3]) * (1.f / CD);
    const float d0 = v.x - mean, d1 = v.y - mean, d2 = v.z - mean, d3 = v.w - mean;
    float ss = d0 * d0 + d1 * d1 + d2 * d2 + d3 * d3;
#pragma unroll
    for (int off = 32; off; off >>= 1) ss += __shfl_xor(ss, off, 64);
    if ((tid & 63) == 0) red[4 + (tid >> 6)] = ss;
    __syncthreads();
    const float var  = (red[4] + red[5] + red[6] + red[7]) * (1.f / CD);
    const float rstd = rsqrtf(var + 1e-12f);
    const float4 gv = ((const float4*)g)[tid];
    const float4 bv = ((const float4*)bb)[tid];
    float4 o;
    o.x = d0 * rstd * gv.x + bv.x;
    o.y = d1 * rstd * gv.y + bv.y;
    o.z = d2 * rstd * gv.z + bv.z;
    o.w = d3 * rstd * gv.w + bv.w;
    ((float4*)(y + (size_t)row * CD))[tid] = o;
    if (yb) {
        ushort4 ob;
        ob.x = f2b(o.x); ob.y = f2b(o.y); ob.z = f2b(o.z); ob.w = f2b(o.w);
        ((ushort4*)(yb + (size_t)row * CD))[tid] = ob;
    }
}

// ---------------------------------------------------------------------------
// Workspace layout (MiB):
//  [0,8) cur f32 | [8,16) qh f32 | [16,20) khb bf16 | [20,24) vhb bf16
//  [24,32) krb bf16 | [32,40) wbuf bf16 | [40,44) vec_b bf16 | [44,52) ax f32
//  [52,60) xb f32 | [60,64) cur_b/xb_b bf16 | [64,72) pos_b bf16
//  [72,72.25) efb | [72.25,72.5) segm u64 bitmask
//  ffb bf16 [8,24) aliases qh/khb/vhb (dead at FFN time)
// ---------------------------------------------------------------------------
extern "C" void kernel_launch(void* const* d_in, const int* in_sizes, int n_in,
                              void* d_out, int out_size, void* d_ws, size_t ws_size,
                              hipStream_t stream)
{
    const float* h       = (const float*)d_in[0];
    const float* pos_emb = (const float*)d_in[1];
    const float* seg_mat = (const float*)d_in[3];
    const float* Wq  = (const float*)d_in[4];
    const float* Wk  = (const float*)d_in[5];
    const float* Wv  = (const float*)d_in[6];
    const float* Wo  = (const float*)d_in[7];
    const float* Wr  = (const float*)d_in[8];
    const float* rwb = (const float*)d_in[9];
    const float* rrb = (const float*)d_in[10];
    const float* rsb = (const float*)d_in[11];
    const float* sege = (const float*)d_in[12];
    const float* ln1g = (const float*)d_in[13];
    const float* ln1b = (const float*)d_in[14];
    const float* fw1  = (const float*)d_in[15];
    const float* fb1  = (const float*)d_in[16];
    const float* fw2  = (const float*)d_in[17];
    const float* fb2  = (const float*)d_in[18];
    const float* ln2g = (const float*)d_in[19];
    const float* ln2b = (const float*)d_in[20];
    float* out = (float*)d_out;

    char* base = (char*)d_ws;
    const size_t MB = 1u << 20;
    float* cur  = (float*)(base + 0 * MB);
    float* qh   = (float*)(base + 8 * MB);
    __bf16* khb = (__bf16*)(base + 16 * MB);
    __bf16* vhb = (__bf16*)(base + 20 * MB);
    __bf16* krb = (__bf16*)(base + 24 * MB);
    unsigned short* wbuf = (unsigned short*)(base + 32 * MB);
    __bf16* vec_b = (__bf16*)(base + 40 * MB);
    float* ax   = (float*)(base + 44 * MB);
    float* xb   = (float*)(base + 52 * MB);
    unsigned short* curxb_b = (unsigned short*)(base + 60 * MB);  // cur_b / xb_b
    unsigned short* pos_b = (unsigned short*)(base + 64 * MB);
    float* efb  = (float*)(base + 72 * MB);
    unsigned long long* segm = (unsigned long long*)(base + 72 * MB + (1u << 18));
    __bf16* ffb = (__bf16*)(base + 8 * MB);   // aliases qh/khb/vhb

    hipMemcpyAsync(cur, h, (size_t)CS * CB * CD * sizeof(float),
                   hipMemcpyDeviceToDevice, stream);
    convert_f2b_kernel<<<(CS * CB * CD / 4) / 256, 256, 0, stream>>>(
        h, curxb_b, CS * CB * CD / 4);
    convert_f2b_kernel<<<(CR * CB * CD / 4) / 256, 256, 0, stream>>>(
        pos_emb, pos_b, CR * CB * CD / 4);
    segpack_bits_kernel<<<(CB * CS * 16) / 256, 256, 0, stream>>>(seg_mat, segm);

    const int MQ = CS * CB;   // 2048
    for (int l = 0; l < CL; ++l) {
        const size_t wOff = (size_t)l * CD * CN * CDH;
        // fused QKV: Bt = [WqT ; WkT ; WvT], outputs qh f32 + khb/vhb bf16
        transpose_f2b_kernel<<<dim3(32, 32), 256, 0, stream>>>(Wq + wOff, wbuf, CD, CD);
        transpose_f2b_kernel<<<dim3(32, 32), 256, 0, stream>>>(Wk + wOff, wbuf + 1024 * 1024, CD, CD);
        transpose_f2b_kernel<<<dim3(32, 32), 256, 0, stream>>>(Wv + wOff, wbuf + 2 * 1024 * 1024, CD, CD);
        mgemm<4, 4, 16><<<dim3(3072 / 128, MQ / 128), 256, 0, stream>>>(
            (const __bf16*)curxb_b, (const __bf16*)wbuf, qh, khb, vhb,
            MQ, 3072, CD, nullptr, nullptr);
        // R projection -> krb bf16
        transpose_f2b_kernel<<<dim3(32, 32), 256, 0, stream>>>(Wr + wOff, wbuf, CD, CD);
        mgemm<4, 4, 8><<<dim3(1024 / 128, (CR * CB) / 128), 256, 0, stream>>>(
            (const __bf16*)pos_b, (const __bf16*)wbuf, nullptr, krb, nullptr,
            CR * CB, CD, CD, nullptr, nullptr);
        ef_kernel<<<(CS * CB * CN) / 256, 256, 0, stream>>>(
            qh, rsb + (size_t)l * CN * CDH, sege + (size_t)l * 2 * CN * CDH, efb);
        attn_mfma_kernel<<<dim3(CB * CN, CS / 64), 256, 0, stream>>>(
            qh, khb, vhb, krb, efb, segm,
            rwb + (size_t)l * CN * CDH, rrb + (size_t)l * CN * CDH, vec_b);
        // Wo projection + residual (Wo already [h][n*d] = Bt layout)
        convert_f2b_kernel<<<(CD * CD / 4) / 256, 256, 0, stream>>>(Wo + wOff, wbuf, CD * CD / 4);
        mgemm<2, 4, 4><<<dim3(1024 / 128, MQ / 64), 256, 0, stream>>>(
            vec_b, (const __bf16*)wbuf, ax, nullptr, nullptr,
            MQ, CD, CD, nullptr, cur);
        ln_kernel<<<MQ, 256, 0, stream>>>(ax, xb, curxb_b, ln1g + l * CD, ln1b + l * CD);
        // FFN
        transpose_f2b_kernel<<<dim3(CDI / 32, CD / 32), 256, 0, stream>>>(
            fw1 + (size_t)l * CD * CDI, wbuf, CD, CDI);
        mgemm<4, 4, 1 | 2 | 8><<<dim3(CDI / 128, MQ / 128), 256, 0, stream>>>(
            (const __bf16*)curxb_b, (const __bf16*)wbuf, nullptr, ffb, nullptr,
            MQ, CDI, CD, fb1 + l * CDI, nullptr);
        transpose_f2b_kernel<<<dim3(CD / 32, CDI / 32), 256, 0, stream>>>(
            fw2 + (size_t)l * CDI * CD, wbuf, CDI, CD);
        mgemm<2, 4, 1 | 4><<<dim3(CD / 128, MQ / 64), 256, 0, stream>>>(
            ffb, (const __bf16*)wbuf, ax, nullptr, nullptr,
            MQ, CD, CDI, fb2 + l * CD, xb);
        if (l == CL - 1)
            ln_kernel<<<MQ, 256, 0, stream>>>(ax, out, nullptr, ln2g + l * CD, ln2b + l * CD);
        else
            ln_kernel<<<MQ, 256, 0, stream>>>(ax, cur, curxb_b, ln2g + l * CD, ln2b + l * CD);
    }
}

// Round 7
// 780.979 us; speedup vs baseline: 1.1181x; 1.0276x over previous
//
#include <hip/hip_runtime.h>
#include <hip/hip_bf16.h>
#include <math.h>

#define CS  1024
#define CB  2
#define CD  1024
#define CN  16
#define CDH 64
#define CDI 4096
#define CR  2048
#define CL  2

typedef __bf16 bf16x8 __attribute__((ext_vector_type(8)));
typedef float  f32x4  __attribute__((ext_vector_type(4)));

__device__ __forceinline__ unsigned short f2b(float f) {
    unsigned int u = __float_as_uint(f);
    u += 0x7FFF + ((u >> 16) & 1);          // RNE
    return (unsigned short)(u >> 16);
}

// async global->LDS 16B per lane: lane i lands at ldsbase + i*16 (wave-uniform base)
__device__ __forceinline__ void gl_lds16(const void* g, void* l) {
    __builtin_amdgcn_global_load_lds(
        (const __attribute__((address_space(1))) unsigned int*)g,
        (__attribute__((address_space(3))) unsigned int*)l, 16, 0, 0);
}

// ---------------------------------------------------------------------------
// flat fp32 -> bf16 convert (x4)
// ---------------------------------------------------------------------------
__global__ __launch_bounds__(256) void convert_f2b_kernel(
    const float* __restrict__ in, unsigned short* __restrict__ out, int n4)
{
    const int i = blockIdx.x * 256 + threadIdx.x;
    if (i >= n4) return;
    const float4 v = ((const float4*)in)[i];
    ushort4 o;
    o.x = f2b(v.x); o.y = f2b(v.y); o.z = f2b(v.z); o.w = f2b(v.w);
    ((ushort4*)out)[i] = o;
}

// ---------------------------------------------------------------------------
// fp32 [K,N] -> bf16 [N,K] transpose-convert (generic shape)
// ---------------------------------------------------------------------------
__global__ __launch_bounds__(256) void transpose_f2b_kernel(
    const float* __restrict__ in, unsigned short* __restrict__ out, int K, int N)
{
    __shared__ unsigned short t[32][33];
    const int k0 = blockIdx.y * 32, n0 = blockIdx.x * 32;
    const int c = threadIdx.x & 31, r0 = threadIdx.x >> 5;
    for (int r = r0; r < 32; r += 8)
        t[r][c] = f2b(in[(size_t)(k0 + r) * N + n0 + c]);
    __syncthreads();
    for (int r = r0; r < 32; r += 8)
        out[(size_t)(n0 + r) * K + k0 + c] = t[c][r];
}

// ---------------------------------------------------------------------------
// batched 1024x1024 transpose-convert: z selects one of 4 weight matrices
// ---------------------------------------------------------------------------
__global__ __launch_bounds__(256) void transpose4_f2b_kernel(
    const float* __restrict__ W0, const float* __restrict__ W1,
    const float* __restrict__ W2, const float* __restrict__ W3,
    unsigned short* __restrict__ out)
{
    __shared__ unsigned short t[32][33];
    const float* in = (blockIdx.z == 0) ? W0 : (blockIdx.z == 1) ? W1
                     : (blockIdx.z == 2) ? W2 : W3;
    unsigned short* o = out + (size_t)blockIdx.z * (1024 * 1024);
    const int k0 = blockIdx.y * 32, n0 = blockIdx.x * 32;
    const int c = threadIdx.x & 31, r0 = threadIdx.x >> 5;
    for (int r = r0; r < 32; r += 8)
        t[r][c] = f2b(in[(size_t)(k0 + r) * 1024 + n0 + c]);
    __syncthreads();
    for (int r = r0; r < 32; r += 8)
        o[(size_t)(n0 + r) * 1024 + k0 + c] = t[c][r];
}

// ---------------------------------------------------------------------------
// m97-style bf16 MFMA GEMM: C = A[M,K] @ Bt[N,K]^T, global_load_lds staging.
// EPI bits: 1=bias 2=gelu 4=res 8=bf16 out(D1) 16=split3 (C0 fp32|D1|D2 bf16)
// ---------------------------------------------------------------------------
template<int FM, int FN, int EPI>
__global__ __launch_bounds__(256) void mgemm(
    const __bf16* __restrict__ A, const __bf16* __restrict__ Bt,
    float* __restrict__ C0, __bf16* __restrict__ D1, __bf16* __restrict__ D2,
    int M, int N, int K,
    const float* __restrict__ bias, const float* __restrict__ res)
{
    constexpr int TM = 32 * FM, TN = 32 * FN;
    __shared__ __align__(16) __bf16 As[TM * 32];
    __shared__ __align__(16) __bf16 Bs[TN * 32];
    const int tid  = threadIdx.x;
    const int wave = tid >> 6, lane = tid & 63;
    const int q = lane >> 4, p = lane & 15;
    const int m0 = blockIdx.y * TM, n0 = blockIdx.x * TN;
    const int wm = (wave & 1) * (16 * FM);
    const int wn = (wave >> 1) * (16 * FN);
    const int lrow = lane >> 2;          // 0..15
    const int lcol = (lane & 3) * 8;     // 0,8,16,24

    f32x4 acc[FM][FN];
#pragma unroll
    for (int i = 0; i < FM; ++i)
#pragma unroll
        for (int j = 0; j < FN; ++j) {
            acc[i][j][0] = 0.f; acc[i][j][1] = 0.f;
            acc[i][j][2] = 0.f; acc[i][j][3] = 0.f;
        }

    for (int k0 = 0; k0 < K; k0 += 32) {
#pragma unroll
        for (int c = wave; c < TM / 16; c += 4)
            gl_lds16(A + (size_t)(m0 + c * 16 + lrow) * K + k0 + lcol,
                     As + c * 16 * 32);
#pragma unroll
        for (int c = wave; c < TN / 16; c += 4)
            gl_lds16(Bt + (size_t)(n0 + c * 16 + lrow) * K + k0 + lcol,
                     Bs + c * 16 * 32);
        __syncthreads();
        bf16x8 af[FM], bfr[FN];
#pragma unroll
        for (int i = 0; i < FM; ++i)
            af[i] = *(const bf16x8*)(As + (wm + i * 16 + p) * 32 + q * 8);
#pragma unroll
        for (int j = 0; j < FN; ++j)
            bfr[j] = *(const bf16x8*)(Bs + (wn + j * 16 + p) * 32 + q * 8);
#pragma unroll
        for (int i = 0; i < FM; ++i)
#pragma unroll
            for (int j = 0; j < FN; ++j)
                acc[i][j] = __builtin_amdgcn_mfma_f32_16x16x32_bf16(
                    af[i], bfr[j], acc[i][j], 0, 0, 0);
        __syncthreads();
    }

    // C/D layout: col = lane&15, row = (lane>>4)*4 + reg
#pragma unroll
    for (int i = 0; i < FM; ++i) {
#pragma unroll
        for (int j = 0; j < FN; ++j) {
            const int col = n0 + wn + j * 16 + p;
            const float bv = (EPI & 1) ? bias[col] : 0.0f;
#pragma unroll
            for (int r = 0; r < 4; ++r) {
                const int row = m0 + wm + i * 16 + q * 4 + r;
                float v = acc[i][j][r] + bv;
                if (EPI & 2) v = 0.5f * v * (1.0f + erff(v * 0.70710678118654752f));
                if (EPI & 4) v += res[(size_t)row * N + col];
                if (EPI & 16) {
                    if (col < 1024)       C0[(size_t)row * 1024 + col] = v;
                    else if (col < 2048)  D1[(size_t)row * 1024 + col - 1024] = (__bf16)v;
                    else                  D2[(size_t)row * 1024 + col - 2048] = (__bf16)v;
                } else if (EPI & 8) {
                    D1[(size_t)row * N + col] = (__bf16)v;
                } else {
                    C0[(size_t)row * N + col] = v;
                }
            }
        }
    }
}

// ---------------------------------------------------------------------------
// seg_mat[S,S,B,2] -> u64 bitmask segm[b][i][j/64]
// ---------------------------------------------------------------------------
__global__ __launch_bounds__(256) void segpack_bits_kernel(
    const float* __restrict__ seg_mat, unsigned long long* __restrict__ segm)
{
    const int idx = blockIdx.x * 256 + threadIdx.x;   // < B*S*16 = 32768
    const int b   = idx / (CS * 16);
    const int rem = idx - b * (CS * 16);
    const int i   = rem >> 4;
    const int wd  = rem & 15;
    unsigned long long m = 0;
#pragma unroll 8
    for (int jj = 0; jj < 64; ++jj) {
        const float f = seg_mat[(((size_t)i * CS + (wd * 64 + jj)) * CB + b) * 2 + 1];
        m |= (unsigned long long)(f > 0.5f) << jj;
    }
    segm[idx] = m;
}

// ---------------------------------------------------------------------------
// ef[s][i,b,n] = sum_d (qh + r_s_bias) * seg_embed[s]
// ---------------------------------------------------------------------------
__global__ __launch_bounds__(256) void ef_kernel(
    const float* __restrict__ qh, const float* __restrict__ rsb,
    const float* __restrict__ sege, float* __restrict__ ef)
{
    const int idx = blockIdx.x * 256 + threadIdx.x;
    const int n = idx & (CN - 1);
    const float* qp = qh + (size_t)idx * CDH;
    const float* sb = rsb + n * CDH;
    const float* s0 = sege + n * CDH;
    const float* s1 = sege + (CN + n) * CDH;
    float e0 = 0.f, e1 = 0.f;
#pragma unroll
    for (int d = 0; d < CDH; ++d) {
        const float qv = qp[d] + sb[d];
        e0 = fmaf(qv, s0[d], e0);
        e1 = fmaf(qv, s1[d], e1);
    }
    ef[idx] = e0;
    ef[CS * CB * CN + idx] = e1;
}

// ---------------------------------------------------------------------------
// Split-j MFMA flash attention. Block = (bn, chunk). Chunk = <=4 j-tiles of
// one i-tile. Writes unnormalized partial O (bf16) + m/l to scratch.
// Chunk table ordered heavy-first. LDS 46080 B.
// Default __launch_bounds__(256) (R4: ",3" caused spills).
// ---------------------------------------------------------------------------
#define VSTR 48
#define PSTR 72

__device__ const unsigned char g_it_tab[40] = {
    15,15,15,15, 14,14,14, 13,13,13, 12,12,12, 11,11,11,
    10,10, 9,9, 8,8, 7,7, 6, 5, 4, 3,
    14, 10, 6, 2, 13, 9, 5, 1, 12, 8, 4, 0 };
__device__ const unsigned char g_c_tab[40] = {
     0, 1, 2, 3,  0, 1, 2,  0, 1, 2,  0, 1, 2,  0, 1, 2,
     0, 1, 0, 1, 0, 1, 0, 1, 0, 0, 0, 0,
     3, 2, 1, 0,  3, 2, 1, 0,  3, 2, 1, 0 };

__global__ __launch_bounds__(256) void attn_mfma_kernel(
    const float* __restrict__ qh, const __bf16* __restrict__ khb,
    const __bf16* __restrict__ vhb, const __bf16* __restrict__ krb,
    const float* __restrict__ efb, const unsigned long long* __restrict__ segm,
    const float* __restrict__ rwb, const float* __restrict__ rrb,
    __bf16* __restrict__ Opart, float* __restrict__ ml)
{
    __shared__ __align__(16) char smem[46080];
    __bf16* Pl  = (__bf16*)(smem);             // [4][16][PSTR]  9216 B
    __bf16* Ks  = (__bf16*)(smem + 9216);      // [2][64][32]    8192 B
    __bf16* Vt  = (__bf16*)(smem + 17408);     // [2][64][VSTR] 12288 B
    __bf16* Krs = (__bf16*)(smem + 29696);     // [2][128][32]  16384 B

    const int bn = blockIdx.x;
    const int b = bn >> 4, n = bn & 15;
    const int itile = g_it_tab[blockIdx.y];
    const int ck    = g_c_tab[blockIdx.y];
    const int i0 = itile * 64;
    const int t0 = ck * 4;
    const int tend = min(t0 + 4, itile + 1);
    const int tid = threadIdx.x;
    const int w = tid >> 6;
    const int lane = tid & 63;
    const int p = lane & 15, q = lane >> 4;
    const int lrow = lane >> 2;          // 0..15
    const int lcol = (lane & 3) * 8;     // 0,8,16,24
    const size_t rstride = (size_t)CB * CN * CDH;

    // persistent Q fragments (A-layout), pre-scaled by 1/8 (exact)
    bf16x8 qwF[2], qrF[2];
    {
        const float* qrow = qh + (((size_t)(i0 + 16 * w + p) * CB + b) * CN + n) * CDH;
        const float* rw = rwb + n * CDH;
        const float* rr = rrb + n * CDH;
#pragma unroll
        for (int ks = 0; ks < 2; ++ks)
#pragma unroll
            for (int t = 0; t < 8; ++t) {
                const int d = ks * 32 + q * 8 + t;
                const float v = qrow[d];
                qwF[ks][t] = (__bf16)((v + rw[d]) * 0.125f);
                qrF[ks][t] = (__bf16)((v + rr[d]) * 0.125f);
            }
    }
    float ef0r[4], efd[4];
#pragma unroll
    for (int r = 0; r < 4; ++r) {
        const size_t e = ((size_t)(i0 + 16 * w + 4 * q + r) * CB + b) * CN + n;
        const float e0 = efb[e];
        ef0r[r] = e0 * 0.125f;
        efd[r]  = (efb[(size_t)CS * CB * CN + e] - e0) * 0.125f;
    }

    f32x4 opv[4];
    float mrow[4], lrow4[4];
#pragma unroll
    for (int nf = 0; nf < 4; ++nf) { opv[nf][0]=0.f; opv[nf][1]=0.f; opv[nf][2]=0.f; opv[nf][3]=0.f; }
#pragma unroll
    for (int r = 0; r < 4; ++r) { mrow[r] = -3.0e38f; lrow4[r] = 0.f; }

    const unsigned long long* sgm = segm + (size_t)b * CS * 16;
    const int wbase = 48 - 16 * w;

    for (int jt = t0; jt < tend; ++jt) {
        const int j0 = jt * 64;
        const int gs = j0 + CS - i0 - 63;      // in [1, 961]

        unsigned long long segw[4];
        const int wi = j0 >> 6;
#pragma unroll
        for (int r = 0; r < 4; ++r)
            segw[r] = sgm[(size_t)(i0 + 16 * w + 4 * q + r) * 16 + wi];

        // ---- stage K and Kr via global_load_lds, V via manual transpose ----
#pragma unroll
        for (int c = w; c < 8; c += 4) {
            const int h = c & 1, grp = c >> 1;
            gl_lds16(khb + (size_t)(j0 + grp * 16 + lrow) * rstride
                         + (size_t)((b * CN + n) * CDH) + h * 32 + lcol,
                     Ks + h * (64 * 32) + grp * (16 * 32));
        }
#pragma unroll
        for (int c = w; c < 16; c += 4) {
            const int h = c & 1, grp = c >> 1;
            gl_lds16(krb + (size_t)(gs + grp * 16 + lrow) * rstride
                         + (size_t)((b * CN + n) * CDH) + h * 32 + lcol,
                     Krs + h * (128 * 32) + grp * (16 * 32));
        }
        {
            const int jp = tid >> 3, o = tid & 7;
            const int j = jp * 2;
            const __bf16* vbase = vhb + (size_t)(j0 + j) * rstride
                                + (size_t)((b * CN + n) * CDH) + o * 8;
            union { uint4 u; unsigned short s[8]; } a0, a1;
            a0.u = *(const uint4*)vbase;
            a1.u = *(const uint4*)(vbase + rstride);
            const int jh = j >> 5, jc = j & 31;
#pragma unroll
            for (int tt = 0; tt < 8; ++tt) {
                const int t = (tt + o) & 7;
                const unsigned int dw = (unsigned int)a0.s[t] | ((unsigned int)a1.s[t] << 16);
                *(unsigned int*)(Vt + jh * (64 * VSTR) + (o * 8 + t) * VSTR + jc) = dw;
            }
        }
        __syncthreads();

        // ---- ac (8 MFMA) + bd raw band (10 MFMA) ----
        f32x4 ac[4], rawacc[5];
#pragma unroll
        for (int nf = 0; nf < 4; ++nf) { ac[nf][0]=0.f; ac[nf][1]=0.f; ac[nf][2]=0.f; ac[nf][3]=0.f; }
#pragma unroll
        for (int t = 0; t < 5; ++t) { rawacc[t][0]=0.f; rawacc[t][1]=0.f; rawacc[t][2]=0.f; rawacc[t][3]=0.f; }
#pragma unroll
        for (int ks = 0; ks < 2; ++ks) {
#pragma unroll
            for (int nf = 0; nf < 4; ++nf) {
                const bf16x8 bf = *(const bf16x8*)(Ks + ks * (64 * 32) + (nf * 16 + p) * 32 + q * 8);
                ac[nf] = __builtin_amdgcn_mfma_f32_16x16x32_bf16(qwF[ks], bf, ac[nf], 0, 0, 0);
            }
#pragma unroll
            for (int t = 0; t < 5; ++t) {
                const bf16x8 bf = *(const bf16x8*)(Krs + ks * (128 * 32) + (wbase + t * 16 + p) * 32 + q * 8);
                rawacc[t] = __builtin_amdgcn_mfma_f32_16x16x32_bf16(qrF[ks], bf, rawacc[t], 0, 0, 0);
            }
        }

        // ---- rel-shift via shuffles ----
        float bd[4][4];
#pragma unroll
        for (int r = 0; r < 4; ++r) {
            const int rl = 4 * q + r;
            const int delta = p + 15 - rl;
            const int srcl = (q << 4) | (delta & 15);
            float sh[5];
#pragma unroll
            for (int t = 0; t < 5; ++t) sh[t] = __shfl(rawacc[t][r], srcl);
            const int hi = delta >> 4;
#pragma unroll
            for (int nf = 0; nf < 4; ++nf)
                bd[nf][r] = hi ? sh[nf + 1] : sh[nf];
        }

        // ---- scores + online softmax ----
        const bool diag = (jt == itile);
        float sc[4][4];
#pragma unroll
        for (int nf = 0; nf < 4; ++nf) {
            const int jj = nf * 16 + p;
#pragma unroll
            for (int r = 0; r < 4; ++r) {
                const int rl = 4 * q + r;
                const float bitf = (float)((segw[r] >> jj) & 1ULL);
                float s = ac[nf][r] + bd[nf][r] + fmaf(efd[r], bitf, ef0r[r]);
                if (diag && jj > 16 * w + rl) s = -3.0e38f;
                sc[nf][r] = s;
            }
        }
        float al[4], ls[4];
#pragma unroll
        for (int r = 0; r < 4; ++r) {
            float m = fmaxf(fmaxf(sc[0][r], sc[1][r]), fmaxf(sc[2][r], sc[3][r]));
#pragma unroll
            for (int off = 1; off < 16; off <<= 1) m = fmaxf(m, __shfl_xor(m, off));
            const float mn = fmaxf(mrow[r], m);
            al[r] = __expf(mrow[r] - mn);
            mrow[r] = mn;
            ls[r] = 0.f;
        }
#pragma unroll
        for (int nf = 0; nf < 4; ++nf)
#pragma unroll
            for (int r = 0; r < 4; ++r) {
                const float pv = __expf(sc[nf][r] - mrow[r]);
                sc[nf][r] = pv;
                ls[r] += pv;
            }
#pragma unroll
        for (int r = 0; r < 4; ++r) {
            float s = ls[r];
#pragma unroll
            for (int off = 1; off < 16; off <<= 1) s += __shfl_xor(s, off);
            lrow4[r] = lrow4[r] * al[r] + s;
#pragma unroll
            for (int nf = 0; nf < 4; ++nf) opv[nf][r] *= al[r];
        }

        // ---- P -> LDS -> A-layout, PV ----
        __bf16* pw = Pl + w * (16 * PSTR);
#pragma unroll
        for (int nf = 0; nf < 4; ++nf)
#pragma unroll
            for (int r = 0; r < 4; ++r)
                pw[(4 * q + r) * PSTR + nf * 16 + p] = (__bf16)sc[nf][r];

#pragma unroll
        for (int ks = 0; ks < 2; ++ks) {
            const bf16x8 pf = *(const bf16x8*)(pw + p * PSTR + ks * 32 + q * 8);
#pragma unroll
            for (int nf = 0; nf < 4; ++nf) {
                const bf16x8 vf = *(const bf16x8*)(Vt + ks * (64 * VSTR) + (nf * 16 + p) * VSTR + q * 8);
                opv[nf] = __builtin_amdgcn_mfma_f32_16x16x32_bf16(pf, vf, opv[nf], 0, 0, 0);
            }
        }
        __syncthreads();
    }

    // ---- write unnormalized partial O (bf16) + m/l ----
    const int cb = bn * 64 + itile * 4 + ck;
    __bf16* od = Opart + (size_t)cb * 4096;
#pragma unroll
    for (int r = 0; r < 4; ++r) {
        const int row = 16 * w + 4 * q + r;
#pragma unroll
        for (int nf = 0; nf < 4; ++nf)
            od[row * 64 + nf * 16 + p] = (__bf16)opv[nf][r];
        if (p == 0) {
            ml[cb * 128 + row] = mrow[r];
            ml[cb * 128 + 64 + row] = lrow4[r];
        }
    }
}

// ---------------------------------------------------------------------------
// Combine split-j partials -> vec_b bf16. Block per (bn, itile).
// ---------------------------------------------------------------------------
__global__ __launch_bounds__(256) void attn_combine_kernel(
    const __bf16* __restrict__ Opart, const float* __restrict__ ml,
    __bf16* __restrict__ vecb)
{
    const int bn = blockIdx.x, b = bn >> 4, n = bn & 15;
    const int itile = blockIdx.y, i0 = itile * 64;
    const int nc = (itile >> 2) + 1;
    const int tid = threadIdx.x;
    const int row = tid >> 2, cg = (tid & 3) << 4;
    const int cb0 = bn * 64 + itile * 4;

    float m = -3.0e38f;
    for (int c = 0; c < nc; ++c) m = fmaxf(m, ml[(cb0 + c) * 128 + row]);
    float l = 0.f;
    float acc[16];
#pragma unroll
    for (int k = 0; k < 16; ++k) acc[k] = 0.f;
    for (int c = 0; c < nc; ++c) {
        const float wgt = __expf(ml[(cb0 + c) * 128 + row] - m);
        l += wgt * ml[(cb0 + c) * 128 + 64 + row];
        const __bf16* src = Opart + (size_t)(cb0 + c) * 4096 + row * 64 + cg;
#pragma unroll
        for (int k = 0; k < 16; ++k) acc[k] += wgt * (float)src[k];
    }
    const float ri = 1.0f / l;
    __bf16* dst = vecb + (((size_t)(i0 + row) * CB + b) * CN + n) * CDH + cg;
#pragma unroll
    for (int k = 0; k < 16; ++k) dst[k] = (__bf16)(acc[k] * ri);
}

// ---------------------------------------------------------------------------
// LayerNorm over D=1024, optional bf16 shadow output
// ---------------------------------------------------------------------------
__global__ __launch_bounds__(256) void ln_kernel(
    const float* __restrict__ x, float* __restrict__ y,
    unsigned short* __restrict__ yb,
    const float* __restrict__ g, const float* __restrict__ bb)
{
    __shared__ float red[8];
    const int row = blockIdx.x;
    const int tid = threadIdx.x;
    const float4 v = ((const float4*)(x + (size_t)row * CD))[tid];
    float s = v.x + v.y + v.z + v.w;
#pragma unroll
    for (int off = 32; off; off >>= 1) s += __shfl_xor(s, off, 64);
    if ((tid & 63) == 0) red[tid >> 6] = s;
    __syncthreads();
    const float mean = (red[0] + red[1] + red[2] + red[3]) * (1.f / CD);
    const float d0 = v.x - mean, d1 = v.y - mean, d2 = v.z - mean, d3 = v.w - mean;
    float ss = d0 * d0 + d1 * d1 + d2 * d2 + d3 * d3;
#pragma unroll
    for (int off = 32; off; off >>= 1) ss += __shfl_xor(ss, off, 64);
    if ((tid & 63) == 0) red[4 + (tid >> 6)] = ss;
    __syncthreads();
    const float var  = (red[4] + red[5] + red[6] + red[7]) * (1.f / CD);
    const float rstd = rsqrtf(var + 1e-12f);
    const float4 gv = ((const float4*)g)[tid];
    const float4 bv = ((const float4*)bb)[tid];
    float4 o;
    o.x = d0 * rstd * gv.x + bv.x;
    o.y = d1 * rstd * gv.y + bv.y;
    o.z = d2 * rstd * gv.z + bv.z;
    o.w = d3 * rstd * gv.w + bv.w;
    ((float4*)(y + (size_t)row * CD))[tid] = o;
    if (yb) {
        ushort4 ob;
        ob.x = f2b(o.x); ob.y = f2b(o.y); ob.z = f2b(o.z); ob.w = f2b(o.w);
        ((ushort4*)(yb + (size_t)row * CD))[tid] = ob;
    }
}

// ---------------------------------------------------------------------------
// Workspace layout (MiB, total 72.5):
//  [0,8) cur f32 | [8,16) qh f32 | [16,20) khb | [20,24) vhb | [24,32) krb
//  [32,40) wbuf bf16 | [40,48) ax f32 | [48,56) xb f32 | [56,60) vec_b bf16
//  [60,64) curxb_b | [64,72) pos_b | [72,72.25) efb | [72.25,72.5) segm
//  Aliases (stream-ordered): Opart bf16 [32,48) = wbuf+ax (dead during attn);
//  ml f32 [48,49) (xb dead during attn); ffb bf16 [8,24) (qh/khb/vhb dead at FFN)
// ---------------------------------------------------------------------------
extern "C" void kernel_launch(void* const* d_in, const int* in_sizes, int n_in,
                              void* d_out, int out_size, void* d_ws, size_t ws_size,
                              hipStream_t stream)
{
    const float* h       = (const float*)d_in[0];
    const float* pos_emb = (const float*)d_in[1];
    const float* seg_mat = (const float*)d_in[3];
    const float* Wq  = (const float*)d_in[4];
    const float* Wk  = (const float*)d_in[5];
    const float* Wv  = (const float*)d_in[6];
    const float* Wo  = (const float*)d_in[7];
    const float* Wr  = (const float*)d_in[8];
    const float* rwb = (const float*)d_in[9];
    const float* rrb = (const float*)d_in[10];
    const float* rsb = (const float*)d_in[11];
    const float* sege = (const float*)d_in[12];
    const float* ln1g = (const float*)d_in[13];
    const float* ln1b = (const float*)d_in[14];
    const float* fw1  = (const float*)d_in[15];
    const float* fb1  = (const float*)d_in[16];
    const float* fw2  = (const float*)d_in[17];
    const float* fb2  = (const float*)d_in[18];
    const float* ln2g = (const float*)d_in[19];
    const float* ln2b = (const float*)d_in[20];
    float* out = (float*)d_out;

    char* base = (char*)d_ws;
    const size_t MB = 1u << 20;
    float* cur  = (float*)(base + 0 * MB);
    float* qh   = (float*)(base + 8 * MB);
    __bf16* khb = (__bf16*)(base + 16 * MB);
    __bf16* vhb = (__bf16*)(base + 20 * MB);
    __bf16* krb = (__bf16*)(base + 24 * MB);
    unsigned short* wbuf = (unsigned short*)(base + 32 * MB);
    float* ax   = (float*)(base + 40 * MB);
    float* xb   = (float*)(base + 48 * MB);
    __bf16* vec_b = (__bf16*)(base + 56 * MB);
    unsigned short* curxb_b = (unsigned short*)(base + 60 * MB);
    unsigned short* pos_b = (unsigned short*)(base + 64 * MB);
    float* efb  = (float*)(base + 72 * MB);
    unsigned long long* segm = (unsigned long long*)(base + 72 * MB + (1u << 18));
    __bf16* Opart = (__bf16*)(base + 32 * MB);   // alias wbuf+ax
    float*  mlb   = (float*)(base + 48 * MB);    // alias xb head
    __bf16* ffb = (__bf16*)(base + 8 * MB);      // alias qh/khb/vhb

    convert_f2b_kernel<<<(CS * CB * CD / 4) / 256, 256, 0, stream>>>(
        h, curxb_b, CS * CB * CD / 4);
    convert_f2b_kernel<<<(CR * CB * CD / 4) / 256, 256, 0, stream>>>(
        pos_emb, pos_b, CR * CB * CD / 4);
    segpack_bits_kernel<<<(CB * CS * 16) / 256, 256, 0, stream>>>(seg_mat, segm);

    const int MQ = CS * CB;   // 2048
    for (int l = 0; l < CL; ++l) {
        const size_t wOff = (size_t)l * CD * CN * CDH;
        // batched weight prep: WqT|WkT|WvT|WrT -> wbuf slots 0..3 (2MB each)
        transpose4_f2b_kernel<<<dim3(32, 32, 4), 256, 0, stream>>>(
            Wq + wOff, Wk + wOff, Wv + wOff, Wr + wOff, wbuf);
        mgemm<4, 4, 16><<<dim3(3072 / 128, MQ / 128), 256, 0, stream>>>(
            (const __bf16*)curxb_b, (const __bf16*)wbuf, qh, khb, vhb,
            MQ, 3072, CD, nullptr, nullptr);
        mgemm<4, 4, 8><<<dim3(1024 / 128, (CR * CB) / 128), 256, 0, stream>>>(
            (const __bf16*)pos_b, (const __bf16*)(wbuf + 3 * 1024 * 1024), nullptr, krb, nullptr,
            CR * CB, CD, CD, nullptr, nullptr);
        ef_kernel<<<(CS * CB * CN) / 256, 256, 0, stream>>>(
            qh, rsb + (size_t)l * CN * CDH, sege + (size_t)l * 2 * CN * CDH, efb);
        attn_mfma_kernel<<<dim3(CB * CN, 40), 256, 0, stream>>>(
            qh, khb, vhb, krb, efb, segm,
            rwb + (size_t)l * CN * CDH, rrb + (size_t)l * CN * CDH, Opart, mlb);
        attn_combine_kernel<<<dim3(CB * CN, CS / 64), 256, 0, stream>>>(
            Opart, mlb, vec_b);
        // Wo projection + residual
        convert_f2b_kernel<<<(CD * CD / 4) / 256, 256, 0, stream>>>(Wo + wOff, wbuf, CD * CD / 4);
        mgemm<2, 4, 4><<<dim3(1024 / 128, MQ / 64), 256, 0, stream>>>(
            vec_b, (const __bf16*)wbuf, ax, nullptr, nullptr,
            MQ, CD, CD, nullptr, (l == 0) ? h : cur);
        ln_kernel<<<MQ, 256, 0, stream>>>(ax, xb, curxb_b, ln1g + l * CD, ln1b + l * CD);
        // FFN
        transpose_f2b_kernel<<<dim3(CDI / 32, CD / 32), 256, 0, stream>>>(
            fw1 + (size_t)l * CD * CDI, wbuf, CD, CDI);
        mgemm<4, 4, 1 | 2 | 8><<<dim3(CDI / 128, MQ / 128), 256, 0, stream>>>(
            (const __bf16*)curxb_b, (const __bf16*)wbuf, nullptr, ffb, nullptr,
            MQ, CDI, CD, fb1 + l * CDI, nullptr);
        transpose_f2b_kernel<<<dim3(CD / 32, CDI / 32), 256, 0, stream>>>(
            fw2 + (size_t)l * CDI * CD, wbuf, CDI, CD);
        mgemm<2, 4, 1 | 4><<<dim3(CD / 128, MQ / 64), 256, 0, stream>>>(
            ffb, (const __bf16*)wbuf, ax, nullptr, nullptr,
            MQ, CD, CDI, fb2 + l * CD, xb);
        if (l == CL - 1)
            ln_kernel<<<MQ, 256, 0, stream>>>(ax, out, nullptr, ln2g + l * CD, ln2b + l * CD);
        else
            ln_kernel<<<MQ, 256, 0, stream>>>(ax, cur, curxb_b, ln2g + l * CD, ln2b + l * CD);
    }
}